// Round 1
// baseline (1446.328 us; speedup 1.0000x reference)
//
#include <hip/hip_runtime.h>
#include <hip/hip_bf16.h>

#define NN   8192
#define NE   262144
#define HD   256
#define NHH  8194   // hh rows = N + 2

// ---------------------------------------------------------------- CSR build
__global__ void hist_kernel(const int* __restrict__ dst, int* __restrict__ cnt, int E) {
    int e = blockIdx.x * blockDim.x + threadIdx.x;
    if (e < E) atomicAdd(&cnt[dst[e]], 1);
}

__global__ __launch_bounds__(1024) void scan_kernel(const int* __restrict__ cnt, int* __restrict__ row_ptr) {
    __shared__ int sdata[1024];
    int tid = threadIdx.x;
    int v[8], local[8];
    int s = 0;
#pragma unroll
    for (int i = 0; i < 8; i++) v[i] = cnt[tid * 8 + i];
#pragma unroll
    for (int i = 0; i < 8; i++) { local[i] = s; s += v[i]; }
    sdata[tid] = s;
    __syncthreads();
    for (int off = 1; off < 1024; off <<= 1) {
        int t = (tid >= off) ? sdata[tid - off] : 0;
        __syncthreads();
        sdata[tid] += t;
        __syncthreads();
    }
    int base = (tid == 0) ? 0 : sdata[tid - 1];
#pragma unroll
    for (int i = 0; i < 8; i++) row_ptr[tid * 8 + i] = base + local[i];
    if (tid == 1023) row_ptr[8192] = sdata[1023];
}

__global__ void copy_int_kernel(const int* __restrict__ a, int* __restrict__ b, int n) {
    int i = blockIdx.x * blockDim.x + threadIdx.x;
    if (i < n) b[i] = a[i];
}

__global__ void fill_kernel(const int* __restrict__ dst, int* __restrict__ cursor, int* __restrict__ eids, int E) {
    int e = blockIdx.x * blockDim.x + threadIdx.x;
    if (e < E) {
        int pos = atomicAdd(&cursor[dst[e]], 1);
        eids[pos] = e;
    }
}

// ------------------------------------------------------------- segment sums
// aggE[n][f] = sum over edges e with dst==n of edge_attr[e][f]   (64 feats)
__global__ __launch_bounds__(64) void segsum64_kernel(const int* __restrict__ row_ptr,
                                                      const int* __restrict__ eids,
                                                      const float* __restrict__ ea,
                                                      float* __restrict__ out) {
    int n = blockIdx.x;
    int f = threadIdx.x;
    int b = row_ptr[n], e = row_ptr[n + 1];
    float acc = 0.f;
    for (int i = b; i < e; ++i) {
        int ee = eids[i];
        acc += ea[(size_t)ee * 64 + f];
    }
    out[(size_t)n * 64 + f] = acc;
}

// agg[n][f] = sum over edges e with dst==n of T[src[e]][f]   (256 feats)
__global__ __launch_bounds__(256) void segsum256_kernel(const int* __restrict__ row_ptr,
                                                        const int* __restrict__ eids,
                                                        const int* __restrict__ src,
                                                        const float* __restrict__ T,
                                                        float* __restrict__ out) {
    int n = blockIdx.x;
    int f = threadIdx.x;
    int b = row_ptr[n], e = row_ptr[n + 1];
    float acc = 0.f;
    for (int i = b; i < e; ++i) {
        int ee = eids[i];
        int s  = src[ee];
        acc += T[(size_t)s * HD + f];
    }
    out[(size_t)n * HD + f] = acc;
}

// ----------------------------------------------------------------- fp32 GEMM
// C[M x N] = act( (A [+ A2]) @ W^T + bias )   W is [N x K] row-major (ldw)
// flags: 1 = relu, 2 = accumulate into C (no bias/act)
__global__ __launch_bounds__(256) void gemm_kernel(const float* __restrict__ A, int lda,
                                                   const float* __restrict__ A2,
                                                   const float* __restrict__ W, int ldw,
                                                   const float* __restrict__ bias,
                                                   float* __restrict__ C, int ldc,
                                                   int M, int N, int K, int flags) {
    __shared__ float As[16][64];
    __shared__ float Ws[16][64];
    const int tid  = threadIdx.x;
    const int row0 = blockIdx.y * 64;
    const int col0 = blockIdx.x * 64;
    const int lm = tid >> 2;          // 0..63
    const int lk = (tid & 3) * 4;     // 0,4,8,12
    const int tx = tid & 15, ty = tid >> 4;
    float acc[4][4] = {};
    for (int k0 = 0; k0 < K; k0 += 16) {
        float4 av = make_float4(0.f, 0.f, 0.f, 0.f);
        int ar = row0 + lm;
        if (ar < M) {
            av = *(const float4*)(A + (size_t)ar * lda + k0 + lk);
            if (A2) {
                float4 bv = *(const float4*)(A2 + (size_t)ar * lda + k0 + lk);
                av.x += bv.x; av.y += bv.y; av.z += bv.z; av.w += bv.w;
            }
        }
        As[lk + 0][lm] = av.x; As[lk + 1][lm] = av.y; As[lk + 2][lm] = av.z; As[lk + 3][lm] = av.w;
        float4 wv = *(const float4*)(W + (size_t)(col0 + lm) * ldw + k0 + lk);
        Ws[lk + 0][lm] = wv.x; Ws[lk + 1][lm] = wv.y; Ws[lk + 2][lm] = wv.z; Ws[lk + 3][lm] = wv.w;
        __syncthreads();
#pragma unroll
        for (int kk = 0; kk < 16; ++kk) {
            float a0 = As[kk][ty * 4 + 0], a1 = As[kk][ty * 4 + 1];
            float a2 = As[kk][ty * 4 + 2], a3 = As[kk][ty * 4 + 3];
            float b0 = Ws[kk][tx * 4 + 0], b1 = Ws[kk][tx * 4 + 1];
            float b2 = Ws[kk][tx * 4 + 2], b3 = Ws[kk][tx * 4 + 3];
            acc[0][0] += a0 * b0; acc[0][1] += a0 * b1; acc[0][2] += a0 * b2; acc[0][3] += a0 * b3;
            acc[1][0] += a1 * b0; acc[1][1] += a1 * b1; acc[1][2] += a1 * b2; acc[1][3] += a1 * b3;
            acc[2][0] += a2 * b0; acc[2][1] += a2 * b1; acc[2][2] += a2 * b2; acc[2][3] += a2 * b3;
            acc[3][0] += a3 * b0; acc[3][1] += a3 * b1; acc[3][2] += a3 * b2; acc[3][3] += a3 * b3;
        }
        __syncthreads();
    }
#pragma unroll
    for (int i = 0; i < 4; ++i) {
        int r = row0 + ty * 4 + i;
        if (r >= M) continue;
#pragma unroll
        for (int j = 0; j < 4; ++j) {
            int c = col0 + tx * 4 + j;
            float v = acc[i][j];
            if (flags & 2)      v += C[(size_t)r * ldc + c];
            else if (bias)      v += bias[c];
            if (flags & 1)      v = fmaxf(v, 0.f);
            C[(size_t)r * ldc + c] = v;
        }
    }
}

// ----------------------------------------------------------- GRU elementwise
__global__ void gru_combine_kernel(const float* __restrict__ gi, const float* __restrict__ gh,
                                   const float* __restrict__ hprev, float* __restrict__ hout, int total) {
    int idx = blockIdx.x * 256 + threadIdx.x;
    if (idx >= total) return;
    int row = idx >> 8, f = idx & 255;
    size_t b = (size_t)row * 768;
    float ir = gi[b + f], iz = gi[b + 256 + f], inn = gi[b + 512 + f];
    float hr = gh[b + f], hz = gh[b + 256 + f], hn  = gh[b + 512 + f];
    float r = 1.f / (1.f + expf(-(ir + hr)));
    float z = 1.f / (1.f + expf(-(iz + hz)));
    float n = tanhf(inn + r * hn);
    hout[(size_t)row * HD + f] = (1.f - z) * n + z * hprev[(size_t)row * HD + f];
}

// ------------------------------------------------------------------ epilogue
__global__ void hhtail_kernel(const float* __restrict__ rc, const float* __restrict__ si, float* __restrict__ hh) {
    int f = threadIdx.x;
    hh[(size_t)NN * HD + f]       = rc[f];
    hh[(size_t)(NN + 1) * HD + f] = si[f];
}

__global__ __launch_bounds__(256) void alpha_kernel(const float* __restrict__ g1, const float* __restrict__ gw2,
                                                    const float* __restrict__ gb2, const int* __restrict__ rcmask,
                                                    float* __restrict__ coef, int N) {
    int node = blockIdx.x * 4 + (threadIdx.x >> 6);
    int lane = threadIdx.x & 63;
    if (node >= N) return;
    float part = g1[(size_t)node * 128 + lane] * gw2[lane]
               + g1[(size_t)node * 128 + 64 + lane] * gw2[64 + lane];
    for (int off = 32; off > 0; off >>= 1) part += __shfl_down(part, off);
    if (lane == 0) {
        float a = 1.f / (1.f + expf(-(part + gb2[0])));
        coef[node] = rcmask[node] ? 0.f : a;
    }
}

// out[f] += sum_{r in block} coef[r] * X[r][f]   (atomic partials)
__global__ __launch_bounds__(256) void colsum_kernel(const float* __restrict__ X, const float* __restrict__ coef,
                                                     float* __restrict__ out, int rows_total, int rows_per_blk) {
    int f  = threadIdx.x;
    int r0 = blockIdx.x * rows_per_blk;
    int r1 = r0 + rows_per_blk; if (r1 > rows_total) r1 = rows_total;
    float acc = 0.f;
    for (int r = r0; r < r1; ++r) acc += coef[r] * X[(size_t)r * HD + f];
    atomicAdd(&out[f], acc);
}

__global__ __launch_bounds__(256) void sgru_kernel(const float* __restrict__ wsum, const float* __restrict__ rcinit,
                                                   const float* __restrict__ sinit, const float* __restrict__ skipW,
                                                   const float* __restrict__ wih, const float* __restrict__ whh,
                                                   const float* __restrict__ bih, const float* __restrict__ bhh,
                                                   float* __restrict__ hh) {
    __shared__ float vsum[256], mm[256], sh[256];
    int f = threadIdx.x;
    vsum[f] = wsum[f] + rcinit[f];
    sh[f]   = sinit[f];
    __syncthreads();
    float m_ = 0.f;
    for (int k = 0; k < 256; ++k) m_ += skipW[(size_t)f * 256 + k] * vsum[k];
    mm[f] = m_;
    __syncthreads();
    float gir = bih[f], giz = bih[256 + f], gin_ = bih[512 + f];
    float ghr = bhh[f], ghz = bhh[256 + f], ghn  = bhh[512 + f];
    for (int k = 0; k < 256; ++k) {
        float mk = mm[k], sk = sh[k];
        gir  += wih[(size_t)f * 256 + k] * mk;
        giz  += wih[(size_t)(256 + f) * 256 + k] * mk;
        gin_ += wih[(size_t)(512 + f) * 256 + k] * mk;
        ghr  += whh[(size_t)f * 256 + k] * sk;
        ghz  += whh[(size_t)(256 + f) * 256 + k] * sk;
        ghn  += whh[(size_t)(512 + f) * 256 + k] * sk;
    }
    float r = 1.f / (1.f + expf(-(gir + ghr)));
    float z = 1.f / (1.f + expf(-(giz + ghz)));
    float n = tanhf(gin_ + r * ghn);
    hh[(size_t)(NN + 1) * HD + f] = (1.f - z) * n + z * sh[f];
}

__global__ __launch_bounds__(256) void qrow_kernel(const float* __restrict__ hh, const float* __restrict__ qw,
                                                   const float* __restrict__ qb, float* __restrict__ qrow) {
    __shared__ float h[256];
    int f = threadIdx.x;
    h[f] = hh[(size_t)(NN + 1) * HD + f];
    __syncthreads();
    float s = qb[f];
    for (int k = 0; k < 256; ++k) s += qw[(size_t)f * 256 + k] * h[k];
    qrow[f] = s;
}

__global__ __launch_bounds__(256) void logits_kernel(const float* __restrict__ kall, const float* __restrict__ qrow,
                                                     float* __restrict__ logits, int n) {
    int j    = blockIdx.x * 4 + (threadIdx.x >> 6);
    int lane = threadIdx.x & 63;
    if (j >= n) return;
    float part = 0.f;
#pragma unroll
    for (int c = 0; c < 4; ++c) part += kall[(size_t)j * HD + c * 64 + lane] * qrow[c * 64 + lane];
    for (int off = 32; off > 0; off >>= 1) part += __shfl_down(part, off);
    if (lane == 0) logits[j] = part * 0.0625f;   // / sqrt(256)
}

__global__ __launch_bounds__(1024) void softmax_prep_kernel(const float* __restrict__ logits, float* __restrict__ p,
                                                            float* __restrict__ scal, int n) {
    __shared__ float sd[1024];
    int tid = threadIdx.x;
    float mx = -1e30f;
    for (int j = tid; j < n; j += 1024) mx = fmaxf(mx, logits[j]);
    sd[tid] = mx;
    __syncthreads();
    for (int off = 512; off > 0; off >>= 1) { if (tid < off) sd[tid] = fmaxf(sd[tid], sd[tid + off]); __syncthreads(); }
    float m = sd[0];
    __syncthreads();
    float s = 0.f;
    for (int j = tid; j < n; j += 1024) { float e = expf(logits[j] - m); p[j] = e; s += e; }
    sd[tid] = s;
    __syncthreads();
    for (int off = 512; off > 0; off >>= 1) { if (tid < off) sd[tid] += sd[tid + off]; __syncthreads(); }
    if (tid == 0) scal[0] = sd[0];
}

__global__ __launch_bounds__(256) void final_kernel(const float* __restrict__ hh, const float* __restrict__ ow,
                                                    const float* __restrict__ ob, const float* __restrict__ ctx,
                                                    const float* __restrict__ scal, float* __restrict__ out) {
    __shared__ float c[256];
    int f = threadIdx.x;
    c[f] = ctx[f];
    __syncthreads();
    float inv = 1.f / scal[0];
    float d = 0.f;
    for (int k = 0; k < 256; ++k) d += ow[(size_t)f * 256 + k] * c[k];
    float val = hh[(size_t)(NN + 1) * HD + f] + d * inv + ob[f];
    out[f] = fmaxf(val, 0.f);
}

// ---------------------------------------------------------------------------
extern "C" void kernel_launch(void* const* d_in, const int* in_sizes, int n_in,
                              void* d_out, int out_size, void* d_ws, size_t ws_size,
                              hipStream_t stream) {
    const float* x      = (const float*)d_in[0];
    const int*   ei     = (const int*)  d_in[1];
    const float* eattr  = (const float*)d_in[2];
    const int*   rcmask = (const int*)  d_in[3];
    const float* Wmsg1  = (const float*)d_in[4];
    const float* wih1   = (const float*)d_in[5];
    const float* whh1   = (const float*)d_in[6];
    const float* bih1   = (const float*)d_in[7];
    const float* bhh1   = (const float*)d_in[8];
    const float* Wmsg2  = (const float*)d_in[9];
    const float* wih2   = (const float*)d_in[10];
    const float* whh2   = (const float*)d_in[11];
    const float* bih2   = (const float*)d_in[12];
    const float* bhh2   = (const float*)d_in[13];
    const float* ginw1  = (const float*)d_in[14];
    const float* ginb1  = (const float*)d_in[15];
    const float* ginw2  = (const float*)d_in[16];
    const float* ginb2  = (const float*)d_in[17];
    const float* projw  = (const float*)d_in[18];
    const float* projb  = (const float*)d_in[19];
    const float* qw     = (const float*)d_in[20];
    const float* qb     = (const float*)d_in[21];
    const float* kw     = (const float*)d_in[22];
    const float* kb     = (const float*)d_in[23];
    const float* vw     = (const float*)d_in[24];
    const float* vb     = (const float*)d_in[25];
    const float* ow     = (const float*)d_in[26];
    const float* ob     = (const float*)d_in[27];
    const float* gatew1 = (const float*)d_in[28];
    const float* gateb1 = (const float*)d_in[29];
    const float* gatew2 = (const float*)d_in[30];
    const float* gateb2 = (const float*)d_in[31];
    const float* skipW  = (const float*)d_in[32];
    const float* swih   = (const float*)d_in[33];
    const float* swhh   = (const float*)d_in[34];
    const float* sbih   = (const float*)d_in[35];
    const float* sbhh   = (const float*)d_in[36];
    const float* rcinit = (const float*)d_in[37];
    const float* sinit  = (const float*)d_in[38];

    const int* src = ei;           // edge_index[0]
    const int* dst = ei + NE;      // edge_index[1]

    // ---------------- workspace layout (aliased; ~96 MB total) -------------
    char*  w   = (char*)d_ws;
    size_t off = 0;
    auto alloc = [&](size_t bytes) -> void* {
        void* p = w + off;
        off = (off + bytes + 255) & ~(size_t)255;
        return p;
    };
    int*   cnt     = (int*)  alloc((size_t)NN * 4);            // also CSR fill cursor
    int*   row_ptr = (int*)  alloc((size_t)(NN + 1) * 4);
    int*   eids    = (int*)  alloc((size_t)NE * 4);
    float* aggE    = (float*)alloc((size_t)NN * 64 * 4);
    float* aggX    = (float*)alloc((size_t)NN * HD * 4);       // aggX / aggA (tower share)
    float* mbuf    = (float*)alloc((size_t)NN * HD * 4);       // m / aggB
    float* h1      = (float*)alloc((size_t)NN * HD * 4);       // h1 / t_buf
    float* h2      = (float*)alloc((size_t)NN * HD * 4);
    float* ubuf    = (float*)alloc((size_t)NN * HD * 4);
    float* gi      = (float*)alloc((size_t)NN * 768 * 4);      // gi / C768
    float* gh      = (float*)alloc((size_t)NN * 768 * 4);      // gh / (k_all,v_all,g1)
    float* hh      = (float*)alloc((size_t)NHH * HD * 4);
    float* coef    = (float*)alloc((size_t)NN * 4);
    float* wsum    = (float*)alloc(256 * 4);
    float* qrow    = (float*)alloc(256 * 4);
    float* logits  = (float*)alloc((size_t)NHH * 4);
    float* pbuf    = (float*)alloc((size_t)NHH * 4);
    float* scal    = (float*)alloc(256);
    float* ctx     = (float*)alloc(256 * 4);

    float* C768  = gi;
    float* k_all = gh;
    float* v_all = gh + (size_t)NHH * HD;     // 8194*256 floats after k_all
    float* g1    = gh + (size_t)2 * NHH * HD; // after v_all

    auto gemm = [&](const float* A, int lda, const float* A2, const float* W, int ldw,
                    const float* bias, float* C, int ldc, int M, int Nc, int K, int flags) {
        dim3 grid(Nc / 64, (M + 63) / 64);
        gemm_kernel<<<grid, 256, 0, stream>>>(A, lda, A2, W, ldw, bias, C, ldc, M, Nc, K, flags);
    };

    // ------------------------------ CSR build ------------------------------
    hipMemsetAsync(cnt, 0, (size_t)NN * 4, stream);
    hist_kernel<<<NE / 256, 256, 0, stream>>>(dst, cnt, NE);
    scan_kernel<<<1, 1024, 0, stream>>>(cnt, row_ptr);
    copy_int_kernel<<<NN / 256, 256, 0, stream>>>(row_ptr, cnt, NN);   // cursor = row_ptr
    fill_kernel<<<NE / 256, 256, 0, stream>>>(dst, cnt, eids, NE);
    segsum64_kernel<<<NN, 64, 0, stream>>>(row_ptr, eids, eattr, aggE);

    // ------------------------------ DMPNN 1 --------------------------------
    segsum256_kernel<<<NN, 256, 0, stream>>>(row_ptr, eids, src, x, aggX);
    gemm(aggX, HD, nullptr, Wmsg1,       320, nullptr, mbuf, HD, NN, HD, HD, 0);
    gemm(aggE, 64, nullptr, Wmsg1 + 256, 320, nullptr, mbuf, HD, NN, HD, 64, 2);
    gemm(mbuf, HD, nullptr, wih1, HD, bih1, gi, 768, NN, 768, HD, 0);
    gemm(x,    HD, nullptr, whh1, HD, bhh1, gh, 768, NN, 768, HD, 0);
    gru_combine_kernel<<<NN * HD / 256, 256, 0, stream>>>(gi, gh, x, h1, NN * HD);

    // ------------------------------ DMPNN 2 --------------------------------
    segsum256_kernel<<<NN, 256, 0, stream>>>(row_ptr, eids, src, h1, aggX);
    gemm(aggX, HD, nullptr, Wmsg2,       320, nullptr, mbuf, HD, NN, HD, HD, 0);
    gemm(aggE, 64, nullptr, Wmsg2 + 256, 320, nullptr, mbuf, HD, NN, HD, 64, 2);
    gemm(mbuf, HD, nullptr, wih2, HD, bih2, gi, 768, NN, 768, HD, 0);
    gemm(h1,   HD, nullptr, whh2, HD, bhh2, gh, 768, NN, 768, HD, 0);
    gru_combine_kernel<<<NN * HD / 256, 256, 0, stream>>>(gi, gh, h1, h2, NN * HD);

    // ------------------------------ GIN towers -----------------------------
    const size_t WS = (size_t)HD * HD;
    float* tbuf = h1;   // h1 dead, reuse
    float* aggA = aggX; // shared first-hop aggregation of h2
    float* aggB = mbuf; // later-hop aggregations
    segsum256_kernel<<<NN, 256, 0, stream>>>(row_ptr, eids, src, h2, aggA);
    // tower 0 (1 hop)
    gemm(h2, HD, aggA, ginw1 + 0 * WS, HD, ginb1 + 0, ubuf, HD, NN, HD, HD, 1);
    gemm(ubuf, HD, nullptr, ginw2 + 0 * WS, HD, ginb2 + 0, C768 + 0, 768, NN, HD, HD, 0);
    // tower 1 (2 hops)
    gemm(h2, HD, aggA, ginw1 + 1 * WS, HD, ginb1 + 256, ubuf, HD, NN, HD, HD, 1);
    gemm(ubuf, HD, nullptr, ginw2 + 1 * WS, HD, ginb2 + 256, tbuf, HD, NN, HD, HD, 0);
    segsum256_kernel<<<NN, 256, 0, stream>>>(row_ptr, eids, src, tbuf, aggB);
    gemm(tbuf, HD, aggB, ginw1 + 1 * WS, HD, ginb1 + 256, ubuf, HD, NN, HD, HD, 1);
    gemm(ubuf, HD, nullptr, ginw2 + 1 * WS, HD, ginb2 + 256, C768 + 256, 768, NN, HD, HD, 0);
    // tower 2 (3 hops)
    gemm(h2, HD, aggA, ginw1 + 2 * WS, HD, ginb1 + 512, ubuf, HD, NN, HD, HD, 1);
    gemm(ubuf, HD, nullptr, ginw2 + 2 * WS, HD, ginb2 + 512, tbuf, HD, NN, HD, HD, 0);
    segsum256_kernel<<<NN, 256, 0, stream>>>(row_ptr, eids, src, tbuf, aggB);
    gemm(tbuf, HD, aggB, ginw1 + 2 * WS, HD, ginb1 + 512, ubuf, HD, NN, HD, HD, 1);
    gemm(ubuf, HD, nullptr, ginw2 + 2 * WS, HD, ginb2 + 512, tbuf, HD, NN, HD, HD, 0);
    segsum256_kernel<<<NN, 256, 0, stream>>>(row_ptr, eids, src, tbuf, aggB);
    gemm(tbuf, HD, aggB, ginw1 + 2 * WS, HD, ginb1 + 512, ubuf, HD, NN, HD, HD, 1);
    gemm(ubuf, HD, nullptr, ginw2 + 2 * WS, HD, ginb2 + 512, C768 + 512, 768, NN, HD, HD, 0);

    // ------------------------------ mix + hh -------------------------------
    gemm(C768, 768, nullptr, projw, 768, projb, hh, HD, NN, HD, 768, 0);
    hhtail_kernel<<<1, 256, 0, stream>>>(rcinit, sinit, hh);

    // ------------------------------ gate / skip-sum / sGRU -----------------
    gemm(hh, HD, nullptr, gatew1, HD, gateb1, g1, 128, NN, 128, HD, 1);
    alpha_kernel<<<NN / 4, 256, 0, stream>>>(g1, gatew2, gateb2, rcmask, coef, NN);
    hipMemsetAsync(wsum, 0, 256 * 4, stream);
    colsum_kernel<<<64, 256, 0, stream>>>(hh, coef, wsum, NN, 128);
    sgru_kernel<<<1, 256, 0, stream>>>(wsum, rcinit, sinit, skipW, swih, swhh, sbih, sbhh, hh);

    // ------------------------------ attention row --------------------------
    gemm(hh, HD, nullptr, kw, HD, kb, k_all, HD, NHH, HD, HD, 0);
    gemm(hh, HD, nullptr, vw, HD, vb, v_all, HD, NHH, HD, HD, 0);
    qrow_kernel<<<1, 256, 0, stream>>>(hh, qw, qb, qrow);
    logits_kernel<<<(NHH + 3) / 4, 256, 0, stream>>>(k_all, qrow, logits, NHH);
    softmax_prep_kernel<<<1, 1024, 0, stream>>>(logits, pbuf, scal, NHH);
    hipMemsetAsync(ctx, 0, 256 * 4, stream);
    colsum_kernel<<<(NHH + 127) / 128, 256, 0, stream>>>(v_all, pbuf, ctx, NHH, 128);
    final_kernel<<<1, 256, 0, stream>>>(hh, ow, ob, ctx, scal, (float*)d_out);
}

// Round 3
// 1020.474 us; speedup vs baseline: 1.4173x; 1.4173x over previous
//
#include <hip/hip_runtime.h>
#include <hip/hip_bf16.h>

#define NN   8192
#define NE   262144
#define HD   256
#define NHH  8194   // hh rows = N + 2

using f32x4  = __attribute__((ext_vector_type(4))) float;
using bf16x8 = __attribute__((ext_vector_type(8))) short;
typedef unsigned short u16;

__device__ __forceinline__ u16 f2bf(float f) {
    unsigned u = __builtin_bit_cast(unsigned, f);
    u = (u + 0x7FFFu + ((u >> 16) & 1u)) >> 16;
    return (u16)u;
}
__device__ __forceinline__ float bf2f(u16 h) {
    return __builtin_bit_cast(float, (unsigned)h << 16);
}
__device__ __forceinline__ void split1(float a, u16& h, u16& l) {
    h = f2bf(a);
    l = f2bf(a - bf2f(h));   // a - hi is exact in fp32
}
__device__ __forceinline__ void store_split4(u16* hi, u16* lo, size_t off, float4 v) {
    ushort4 h, l;
    split1(v.x, h.x, l.x); split1(v.y, h.y, l.y);
    split1(v.z, h.z, l.z); split1(v.w, h.w, l.w);
    *(ushort4*)(hi + off) = h;
    *(ushort4*)(lo + off) = l;
}

// ---------------------------------------------------------------- CSR build
__global__ void hist_kernel(const int* __restrict__ dst, int* __restrict__ cnt, int E) {
    int e = blockIdx.x * blockDim.x + threadIdx.x;
    if (e < E) atomicAdd(&cnt[dst[e]], 1);
}

__global__ __launch_bounds__(1024) void scan_kernel(const int* __restrict__ cnt, int* __restrict__ row_ptr) {
    __shared__ int sdata[1024];
    int tid = threadIdx.x;
    int v[8], local[8];
    int s = 0;
#pragma unroll
    for (int i = 0; i < 8; i++) v[i] = cnt[tid * 8 + i];
#pragma unroll
    for (int i = 0; i < 8; i++) { local[i] = s; s += v[i]; }
    sdata[tid] = s;
    __syncthreads();
    for (int off = 1; off < 1024; off <<= 1) {
        int t = (tid >= off) ? sdata[tid - off] : 0;
        __syncthreads();
        sdata[tid] += t;
        __syncthreads();
    }
    int base = (tid == 0) ? 0 : sdata[tid - 1];
#pragma unroll
    for (int i = 0; i < 8; i++) row_ptr[tid * 8 + i] = base + local[i];
    if (tid == 1023) row_ptr[8192] = sdata[1023];
}

__global__ void copy_int_kernel(const int* __restrict__ a, int* __restrict__ b, int n) {
    int i = blockIdx.x * blockDim.x + threadIdx.x;
    if (i < n) b[i] = a[i];
}

__global__ void fill_kernel(const int* __restrict__ dst, const int* __restrict__ src,
                            int* __restrict__ cursor, int* __restrict__ eids,
                            int* __restrict__ gsrc, int E) {
    int e = blockIdx.x * blockDim.x + threadIdx.x;
    if (e < E) {
        int pos = atomicAdd(&cursor[dst[e]], 1);
        eids[pos] = e;
        gsrc[pos] = src[e];
    }
}

// ------------------------------------------------- generic fp32 -> bf16 split
__global__ void split_kernel(const float* __restrict__ in, u16* __restrict__ hi,
                             u16* __restrict__ lo, int n) {
    int i = blockIdx.x * 256 + threadIdx.x;
    if (i >= n) return;
    u16 h, l;
    split1(in[i], h, l);
    hi[i] = h; lo[i] = l;
}

// --------------------------------------- segment sum -> split bf16 planes
// out[n] = (self ? T[n] : 0) + sum_{i in [row_ptr[n],row_ptr[n+1])} T[idx[i]]
template <int FEATS>
__global__ __launch_bounds__(256) void segsum_split_kernel(const int* __restrict__ row_ptr,
                                                           const int* __restrict__ idx,
                                                           const float* __restrict__ T,
                                                           u16* __restrict__ outh,
                                                           u16* __restrict__ outl,
                                                           int self) {
    constexpr int LPR   = FEATS / 4;    // threads per row
    constexpr int SLOTS = 256 / LPR;    // concurrent edge slots
    __shared__ float4 part[SLOTS - 1][LPR];
    const int n    = blockIdx.x;
    const int slot = threadIdx.x / LPR;
    const int fl   = threadIdx.x % LPR;
    const int b = row_ptr[n], e = row_ptr[n + 1];
    float4 a0 = make_float4(0.f, 0.f, 0.f, 0.f);
    float4 a1 = make_float4(0.f, 0.f, 0.f, 0.f);
    int i = b + slot;
    for (; i + SLOTS < e; i += 2 * SLOTS) {
        int s0 = idx[i];
        int s1 = idx[i + SLOTS];
        float4 v0 = *(const float4*)(T + (size_t)s0 * FEATS + fl * 4);
        float4 v1 = *(const float4*)(T + (size_t)s1 * FEATS + fl * 4);
        a0.x += v0.x; a0.y += v0.y; a0.z += v0.z; a0.w += v0.w;
        a1.x += v1.x; a1.y += v1.y; a1.z += v1.z; a1.w += v1.w;
    }
    if (i < e) {
        int s0 = idx[i];
        float4 v0 = *(const float4*)(T + (size_t)s0 * FEATS + fl * 4);
        a0.x += v0.x; a0.y += v0.y; a0.z += v0.z; a0.w += v0.w;
    }
    a0.x += a1.x; a0.y += a1.y; a0.z += a1.z; a0.w += a1.w;
    if (slot > 0) part[slot - 1][fl] = a0;
    __syncthreads();
    if (slot == 0) {
#pragma unroll
        for (int t = 0; t < SLOTS - 1; ++t) {
            float4 p = part[t][fl];
            a0.x += p.x; a0.y += p.y; a0.z += p.z; a0.w += p.w;
        }
        if (self) {
            float4 s = *(const float4*)(T + (size_t)n * FEATS + fl * 4);
            a0.x += s.x; a0.y += s.y; a0.z += s.z; a0.w += s.w;
        }
        store_split4(outh, outl, (size_t)n * FEATS + fl * 4, a0);
    }
}

// --------------------------------- split-bf16 3-product MFMA GEMM
// C[M x N] = act( (A ‖ Ab) @ W^T + bias ),  A = Ah + Al (bf16 planes), same W.
// C (fp32) and/or Chi/Clo (split planes) written. flags: 1 = relu.
// Block: 128 rows x 64 cols, 4 waves of 64x32. mfma_f32_16x16x32_bf16.
__global__ __launch_bounds__(256) void hgemm_kernel(
    const u16* __restrict__ Ah, const u16* __restrict__ Al, int lda,
    const u16* __restrict__ Abh, const u16* __restrict__ Abl, int ldab, int Kb,
    const u16* __restrict__ Wh, const u16* __restrict__ Wl, int ldw,
    const float* __restrict__ bias,
    float* __restrict__ C, u16* __restrict__ Chi, u16* __restrict__ Clo, int ldc,
    int M, int K, int flags) {
    const int tid  = threadIdx.x;
    const int wid  = tid >> 6;
    const int lane = tid & 63;
    const int lrow = lane & 15;
    const int koff = (lane >> 4) * 8;
    const int wrow0 = blockIdx.y * 128 + (wid >> 1) * 64;
    const int wcol0 = blockIdx.x * 64 + (wid & 1) * 32;

    f32x4 acc[4][2] = {};
    int rr[4];
#pragma unroll
    for (int fi = 0; fi < 4; ++fi) {
        int r = wrow0 + fi * 16 + lrow;
        rr[fi] = (r < M) ? r : (M - 1);     // clamp reads; stores guarded
    }

    for (int k0 = 0; k0 < K; k0 += 32) {
        bf16x8 ah[4], al[4], wh[2], wl[2];
#pragma unroll
        for (int ci = 0; ci < 2; ++ci) {
            size_t o = (size_t)(wcol0 + ci * 16 + lrow) * ldw + k0 + koff;
            wh[ci] = *(const bf16x8*)(Wh + o);
            wl[ci] = *(const bf16x8*)(Wl + o);
        }
#pragma unroll
        for (int fi = 0; fi < 4; ++fi) {
            size_t o = (size_t)rr[fi] * lda + k0 + koff;
            ah[fi] = *(const bf16x8*)(Ah + o);
            al[fi] = *(const bf16x8*)(Al + o);
        }
#pragma unroll
        for (int fi = 0; fi < 4; ++fi)
#pragma unroll
            for (int ci = 0; ci < 2; ++ci) {
                acc[fi][ci] = __builtin_amdgcn_mfma_f32_16x16x32_bf16(ah[fi], wh[ci], acc[fi][ci], 0, 0, 0);
                acc[fi][ci] = __builtin_amdgcn_mfma_f32_16x16x32_bf16(ah[fi], wl[ci], acc[fi][ci], 0, 0, 0);
                acc[fi][ci] = __builtin_amdgcn_mfma_f32_16x16x32_bf16(al[fi], wh[ci], acc[fi][ci], 0, 0, 0);
            }
    }

    if (Abh) {   // concat segment (edge-attr part of W_msg)
        const u16* W2h = Wh + K;
        const u16* W2l = Wl + K;
        for (int k0 = 0; k0 < Kb; k0 += 32) {
            bf16x8 ah[4], al[4], wh[2], wl[2];
#pragma unroll
            for (int ci = 0; ci < 2; ++ci) {
                size_t o = (size_t)(wcol0 + ci * 16 + lrow) * ldw + k0 + koff;
                wh[ci] = *(const bf16x8*)(W2h + o);
                wl[ci] = *(const bf16x8*)(W2l + o);
            }
#pragma unroll
            for (int fi = 0; fi < 4; ++fi) {
                size_t o = (size_t)rr[fi] * ldab + k0 + koff;
                ah[fi] = *(const bf16x8*)(Abh + o);
                al[fi] = *(const bf16x8*)(Abl + o);
            }
#pragma unroll
            for (int fi = 0; fi < 4; ++fi)
#pragma unroll
                for (int ci = 0; ci < 2; ++ci) {
                    acc[fi][ci] = __builtin_amdgcn_mfma_f32_16x16x32_bf16(ah[fi], wh[ci], acc[fi][ci], 0, 0, 0);
                    acc[fi][ci] = __builtin_amdgcn_mfma_f32_16x16x32_bf16(ah[fi], wl[ci], acc[fi][ci], 0, 0, 0);
                    acc[fi][ci] = __builtin_amdgcn_mfma_f32_16x16x32_bf16(al[fi], wh[ci], acc[fi][ci], 0, 0, 0);
                }
        }
    }

#pragma unroll
    for (int fi = 0; fi < 4; ++fi) {
        int rbase = wrow0 + fi * 16 + (lane >> 4) * 4;
#pragma unroll
        for (int ci = 0; ci < 2; ++ci) {
            int col = wcol0 + ci * 16 + lrow;
#pragma unroll
            for (int j = 0; j < 4; ++j) {
                int r = rbase + j;
                if (r >= M) continue;
                float v = acc[fi][ci][j];
                if (bias)      v += bias[col];
                if (flags & 1) v = fmaxf(v, 0.f);
                size_t o = (size_t)r * ldc + col;
                if (C) C[o] = v;
                if (Chi) { u16 hb, lb; split1(v, hb, lb); Chi[o] = hb; Clo[o] = lb; }
            }
        }
    }
}

// ----------------------------------------------------------- GRU elementwise
__global__ void gru_combine_kernel(const float* __restrict__ gi, const float* __restrict__ gh,
                                   const float* __restrict__ hprev, float* __restrict__ hout,
                                   u16* __restrict__ hhi, u16* __restrict__ hlo, int total) {
    int idx = blockIdx.x * 256 + threadIdx.x;
    if (idx >= total) return;
    int row = idx >> 8, f = idx & 255;
    size_t b = (size_t)row * 768;
    float ir = gi[b + f], iz = gi[b + 256 + f], inn = gi[b + 512 + f];
    float hr = gh[b + f], hz = gh[b + 256 + f], hn  = gh[b + 512 + f];
    float r = 1.f / (1.f + expf(-(ir + hr)));
    float z = 1.f / (1.f + expf(-(iz + hz)));
    float n = tanhf(inn + r * hn);
    float hv = (1.f - z) * n + z * hprev[(size_t)row * HD + f];
    size_t o = (size_t)row * HD + f;
    hout[o] = hv;
    if (hhi) { u16 h, l; split1(hv, h, l); hhi[o] = h; hlo[o] = l; }
}

// ------------------------------------------------------------------ epilogue
__global__ void hhtail_kernel(const float* __restrict__ rc, const float* __restrict__ si,
                              float* __restrict__ hh, u16* __restrict__ hhi, u16* __restrict__ hlo) {
    int f = threadIdx.x;
    size_t o1 = (size_t)NN * HD + f, o2 = (size_t)(NN + 1) * HD + f;
    float a = rc[f], b = si[f];
    hh[o1] = a; hh[o2] = b;
    u16 h, l;
    split1(a, h, l); hhi[o1] = h; hlo[o1] = l;
    split1(b, h, l); hhi[o2] = h; hlo[o2] = l;
}

__global__ __launch_bounds__(256) void alpha_kernel(const float* __restrict__ g1, const float* __restrict__ gw2,
                                                    const float* __restrict__ gb2, const int* __restrict__ rcmask,
                                                    float* __restrict__ coef, int N) {
    int node = blockIdx.x * 4 + (threadIdx.x >> 6);
    int lane = threadIdx.x & 63;
    if (node >= N) return;
    float part = g1[(size_t)node * 128 + lane] * gw2[lane]
               + g1[(size_t)node * 128 + 64 + lane] * gw2[64 + lane];
    for (int off = 32; off > 0; off >>= 1) part += __shfl_down(part, off);
    if (lane == 0) {
        float a = 1.f / (1.f + expf(-(part + gb2[0])));
        coef[node] = rcmask[node] ? 0.f : a;
    }
}

__global__ __launch_bounds__(256) void colsum_kernel(const float* __restrict__ X, const float* __restrict__ coef,
                                                     float* __restrict__ out, int rows_total, int rows_per_blk) {
    int f  = threadIdx.x;
    int r0 = blockIdx.x * rows_per_blk;
    int r1 = r0 + rows_per_blk; if (r1 > rows_total) r1 = rows_total;
    float acc = 0.f;
    for (int r = r0; r < r1; ++r) acc += coef[r] * X[(size_t)r * HD + f];
    atomicAdd(&out[f], acc);
}

__global__ __launch_bounds__(256) void sgru_kernel(const float* __restrict__ wsum, const float* __restrict__ rcinit,
                                                   const float* __restrict__ sinit, const float* __restrict__ skipW,
                                                   const float* __restrict__ wih, const float* __restrict__ whh,
                                                   const float* __restrict__ bih, const float* __restrict__ bhh,
                                                   float* __restrict__ hh, u16* __restrict__ hhi, u16* __restrict__ hlo) {
    __shared__ float vsum[256], mm[256], sh[256];
    int f = threadIdx.x;
    vsum[f] = wsum[f] + rcinit[f];
    sh[f]   = sinit[f];
    __syncthreads();
    float m_ = 0.f;
    for (int k = 0; k < 256; ++k) m_ += skipW[(size_t)f * 256 + k] * vsum[k];
    mm[f] = m_;
    __syncthreads();
    float gir = bih[f], giz = bih[256 + f], gin_ = bih[512 + f];
    float ghr = bhh[f], ghz = bhh[256 + f], ghn  = bhh[512 + f];
    for (int k = 0; k < 256; ++k) {
        float mk = mm[k], sk = sh[k];
        gir  += wih[(size_t)f * 256 + k] * mk;
        giz  += wih[(size_t)(256 + f) * 256 + k] * mk;
        gin_ += wih[(size_t)(512 + f) * 256 + k] * mk;
        ghr  += whh[(size_t)f * 256 + k] * sk;
        ghz  += whh[(size_t)(256 + f) * 256 + k] * sk;
        ghn  += whh[(size_t)(512 + f) * 256 + k] * sk;
    }
    float r = 1.f / (1.f + expf(-(gir + ghr)));
    float z = 1.f / (1.f + expf(-(giz + ghz)));
    float n = tanhf(gin_ + r * ghn);
    float hv = (1.f - z) * n + z * sh[f];
    size_t o = (size_t)(NN + 1) * HD + f;
    hh[o] = hv;
    u16 h, l; split1(hv, h, l); hhi[o] = h; hlo[o] = l;
}

__global__ __launch_bounds__(256) void qrow_kernel(const float* __restrict__ hh, const float* __restrict__ qw,
                                                   const float* __restrict__ qb, float* __restrict__ qrow) {
    __shared__ float h[256];
    int f = threadIdx.x;
    h[f] = hh[(size_t)(NN + 1) * HD + f];
    __syncthreads();
    float s = qb[f];
    for (int k = 0; k < 256; ++k) s += qw[(size_t)f * 256 + k] * h[k];
    qrow[f] = s;
}

__global__ __launch_bounds__(256) void logits_kernel(const float* __restrict__ kall, const float* __restrict__ qrow,
                                                     float* __restrict__ logits, int n) {
    int j    = blockIdx.x * 4 + (threadIdx.x >> 6);
    int lane = threadIdx.x & 63;
    if (j >= n) return;
    float part = 0.f;
#pragma unroll
    for (int c = 0; c < 4; ++c) part += kall[(size_t)j * HD + c * 64 + lane] * qrow[c * 64 + lane];
    for (int off = 32; off > 0; off >>= 1) part += __shfl_down(part, off);
    if (lane == 0) logits[j] = part * 0.0625f;   // / sqrt(256)
}

__global__ __launch_bounds__(1024) void softmax_prep_kernel(const float* __restrict__ logits, float* __restrict__ p,
                                                            float* __restrict__ scal, int n) {
    __shared__ float sd[1024];
    int tid = threadIdx.x;
    float mx = -1e30f;
    for (int j = tid; j < n; j += 1024) mx = fmaxf(mx, logits[j]);
    sd[tid] = mx;
    __syncthreads();
    for (int off = 512; off > 0; off >>= 1) { if (tid < off) sd[tid] = fmaxf(sd[tid], sd[tid + off]); __syncthreads(); }
    float m = sd[0];
    __syncthreads();
    float s = 0.f;
    for (int j = tid; j < n; j += 1024) { float e = expf(logits[j] - m); p[j] = e; s += e; }
    sd[tid] = s;
    __syncthreads();
    for (int off = 512; off > 0; off >>= 1) { if (tid < off) sd[tid] += sd[tid + off]; __syncthreads(); }
    if (tid == 0) scal[0] = sd[0];
}

__global__ __launch_bounds__(256) void final_kernel(const float* __restrict__ hh, const float* __restrict__ ow,
                                                    const float* __restrict__ ob, const float* __restrict__ ctx,
                                                    const float* __restrict__ scal, float* __restrict__ out) {
    __shared__ float c[256];
    int f = threadIdx.x;
    c[f] = ctx[f];
    __syncthreads();
    float inv = 1.f / scal[0];
    float d = 0.f;
    for (int k = 0; k < 256; ++k) d += ow[(size_t)f * 256 + k] * c[k];
    float val = hh[(size_t)(NN + 1) * HD + f] + d * inv + ob[f];
    out[f] = fmaxf(val, 0.f);
}

// ---------------------------------------------------------------------------
extern "C" void kernel_launch(void* const* d_in, const int* in_sizes, int n_in,
                              void* d_out, int out_size, void* d_ws, size_t ws_size,
                              hipStream_t stream) {
    const float* x      = (const float*)d_in[0];
    const int*   ei     = (const int*)  d_in[1];
    const float* eattr  = (const float*)d_in[2];
    const int*   rcmask = (const int*)  d_in[3];
    const float* Wmsg1  = (const float*)d_in[4];
    const float* wih1   = (const float*)d_in[5];
    const float* whh1   = (const float*)d_in[6];
    const float* bih1   = (const float*)d_in[7];
    const float* bhh1   = (const float*)d_in[8];
    const float* Wmsg2  = (const float*)d_in[9];
    const float* wih2   = (const float*)d_in[10];
    const float* whh2   = (const float*)d_in[11];
    const float* bih2   = (const float*)d_in[12];
    const float* bhh2   = (const float*)d_in[13];
    const float* ginw1  = (const float*)d_in[14];
    const float* ginb1  = (const float*)d_in[15];
    const float* ginw2  = (const float*)d_in[16];
    const float* ginb2  = (const float*)d_in[17];
    const float* projw  = (const float*)d_in[18];
    const float* projb  = (const float*)d_in[19];
    const float* qw     = (const float*)d_in[20];
    const float* qb     = (const float*)d_in[21];
    const float* kw     = (const float*)d_in[22];
    const float* kb     = (const float*)d_in[23];
    const float* vw     = (const float*)d_in[24];
    const float* vb     = (const float*)d_in[25];
    const float* ow     = (const float*)d_in[26];
    const float* ob     = (const float*)d_in[27];
    const float* gatew1 = (const float*)d_in[28];
    const float* gateb1 = (const float*)d_in[29];
    const float* gatew2 = (const float*)d_in[30];
    const float* gateb2 = (const float*)d_in[31];
    const float* skipW  = (const float*)d_in[32];
    const float* swih   = (const float*)d_in[33];
    const float* swhh   = (const float*)d_in[34];
    const float* sbih   = (const float*)d_in[35];
    const float* sbhh   = (const float*)d_in[36];
    const float* rcinit = (const float*)d_in[37];
    const float* sinit  = (const float*)d_in[38];

    const int* src = ei;
    const int* dst = ei + NE;

    // ---------------- workspace layout (~104 MB) ---------------------------
    char*  w   = (char*)d_ws;
    size_t off = 0;
    auto alloc = [&](size_t bytes) -> void* {
        void* p = w + off;
        off = (off + bytes + 255) & ~(size_t)255;
        return p;
    };
    int*   cnt     = (int*)alloc((size_t)NN * 4);
    int*   row_ptr = (int*)alloc((size_t)(NN + 1) * 4);
    int*   eids    = (int*)alloc((size_t)NE * 4);
    int*   gsrc    = (int*)alloc((size_t)NE * 4);
    u16*   aeh     = (u16*)alloc((size_t)NN * 64 * 2);     // aggE split
    u16*   ael     = (u16*)alloc((size_t)NN * 64 * 2);
    u16*   shh_    = (u16*)alloc((size_t)NHH * HD * 2);    // shared: x-split / h1-split / hh-split
    u16*   shl_    = (u16*)alloc((size_t)NHH * HD * 2);
    u16*   gsh     = (u16*)alloc((size_t)NN * HD * 2);     // aggX / (t+agg) split
    u16*   gsl     = (u16*)alloc((size_t)NN * HD * 2);
    u16*   msh     = (u16*)alloc((size_t)NN * HD * 2);     // m / u split
    u16*   msl     = (u16*)alloc((size_t)NN * HD * 2);
    float* h1      = (float*)alloc((size_t)NN * HD * 4);   // h1 / t1 / t2b fp32
    float* h2      = (float*)alloc((size_t)NN * HD * 4);   // h2 / t2 fp32
    float* gi      = (float*)alloc((size_t)NN * 768 * 4);  // phase B: C768 split planes
    float* gh      = (float*)alloc((size_t)NN * 768 * 4);  // phase B: k_all, v_all, g1
    float* hh      = (float*)alloc((size_t)NHH * HD * 4);
    float* coef    = (float*)alloc((size_t)NN * 4);
    float* wsum    = (float*)alloc(256 * 4);
    float* qrow    = (float*)alloc(256 * 4);
    float* logits  = (float*)alloc((size_t)NHH * 4);
    float* pbuf    = (float*)alloc((size_t)NHH * 4);
    float* scal    = (float*)alloc(256);
    float* ctx     = (float*)alloc(256 * 4);

    // weight split planes
    auto walloc = [&](size_t nel, u16** h, u16** l) {
        *h = (u16*)alloc(nel * 2); *l = (u16*)alloc(nel * 2);
    };
    u16 *wm1h, *wm1l, *wm2h, *wm2l, *wi1h, *wi1l, *wh1h, *wh1l, *wi2h, *wi2l, *wh2h, *wh2l;
    u16 *g1h, *g1l, *g2h, *g2l, *pjh, *pjl, *gwh, *gwl, *kwh, *kwl, *vwh, *vwl;
    walloc(81920, &wm1h, &wm1l);   walloc(81920, &wm2h, &wm2l);
    walloc(196608, &wi1h, &wi1l);  walloc(196608, &wh1h, &wh1l);
    walloc(196608, &wi2h, &wi2l);  walloc(196608, &wh2h, &wh2l);
    walloc(196608, &g1h, &g1l);    walloc(196608, &g2h, &g2l);
    walloc(196608, &pjh, &pjl);    walloc(32768, &gwh, &gwl);
    walloc(65536, &kwh, &kwl);     walloc(65536, &vwh, &vwl);

    // phase-B aliases
    u16*   c768h = (u16*)gi;
    u16*   c768l = c768h + (size_t)NN * 768;
    float* k_all = gh;
    float* v_all = gh + (size_t)NHH * HD;
    float* g1    = gh + (size_t)2 * NHH * HD;

    auto hg = [&](const u16* Ah, const u16* Al, int lda,
                  const u16* Abh, const u16* Abl, int ldab, int Kb,
                  const u16* Wh, const u16* Wl, int ldw, const float* bias,
                  float* C, u16* Chi, u16* Clo, int ldc,
                  int M, int Nc, int K, int flags) {
        dim3 grid(Nc / 64, (M + 127) / 128);
        hgemm_kernel<<<grid, 256, 0, stream>>>(Ah, Al, lda, Abh, Abl, ldab, Kb,
                                               Wh, Wl, ldw, bias, C, Chi, Clo, ldc, M, K, flags);
    };
    auto split = [&](const float* in, u16* hi, u16* lo, int n) {
        split_kernel<<<(n + 255) / 256, 256, 0, stream>>>(in, hi, lo, n);
    };

    // ------------------------------ CSR build ------------------------------
    hipMemsetAsync(cnt, 0, (size_t)NN * 4, stream);
    hist_kernel<<<NE / 256, 256, 0, stream>>>(dst, cnt, NE);
    scan_kernel<<<1, 1024, 0, stream>>>(cnt, row_ptr);
    copy_int_kernel<<<NN / 256, 256, 0, stream>>>(row_ptr, cnt, NN);
    fill_kernel<<<NE / 256, 256, 0, stream>>>(dst, src, cnt, eids, gsrc, NE);
    segsum_split_kernel<64><<<NN, 256, 0, stream>>>(row_ptr, eids, eattr, aeh, ael, 0);

    // ------------------------------ one-time splits ------------------------
    split(x, shh_, shl_, NN * HD);
    split(Wmsg1, wm1h, wm1l, 81920);   split(Wmsg2, wm2h, wm2l, 81920);
    split(wih1, wi1h, wi1l, 196608);   split(whh1, wh1h, wh1l, 196608);
    split(wih2, wi2h, wi2l, 196608);   split(whh2, wh2h, wh2l, 196608);
    split(ginw1, g1h, g1l, 196608);    split(ginw2, g2h, g2l, 196608);
    split(projw, pjh, pjl, 196608);    split(gatew1, gwh, gwl, 32768);
    split(kw, kwh, kwl, 65536);        split(vw, vwh, vwl, 65536);

    // ------------------------------ DMPNN 1 --------------------------------
    segsum_split_kernel<HD><<<NN, 256, 0, stream>>>(row_ptr, gsrc, x, gsh, gsl, 0);
    hg(gsh, gsl, HD, aeh, ael, 64, 64, wm1h, wm1l, 320, nullptr,
       nullptr, msh, msl, HD, NN, HD, HD, 0);
    hg(msh, msl, HD, nullptr, nullptr, 0, 0, wi1h, wi1l, HD, bih1,
       gi, nullptr, nullptr, 768, NN, 768, HD, 0);
    hg(shh_, shl_, HD, nullptr, nullptr, 0, 0, wh1h, wh1l, HD, bhh1,
       gh, nullptr, nullptr, 768, NN, 768, HD, 0);
    gru_combine_kernel<<<NN * HD / 256, 256, 0, stream>>>(gi, gh, x, h1, shh_, shl_, NN * HD);

    // ------------------------------ DMPNN 2 --------------------------------
    segsum_split_kernel<HD><<<NN, 256, 0, stream>>>(row_ptr, gsrc, h1, gsh, gsl, 0);
    hg(gsh, gsl, HD, aeh, ael, 64, 64, wm2h, wm2l, 320, nullptr,
       nullptr, msh, msl, HD, NN, HD, HD, 0);
    hg(msh, msl, HD, nullptr, nullptr, 0, 0, wi2h, wi2l, HD, bih2,
       gi, nullptr, nullptr, 768, NN, 768, HD, 0);
    hg(shh_, shl_, HD, nullptr, nullptr, 0, 0, wh2h, wh2l, HD, bhh2,
       gh, nullptr, nullptr, 768, NN, 768, HD, 0);
    gru_combine_kernel<<<NN * HD / 256, 256, 0, stream>>>(gi, gh, h1, h2, nullptr, nullptr, NN * HD);

    // ------------------------------ GIN towers -----------------------------
    // s = t + agg(t) computed fp32 inside segsum_split(self=1), then 3-product GEMMs.
    segsum_split_kernel<HD><<<NN, 256, 0, stream>>>(row_ptr, gsrc, h2, gsh, gsl, 1);
    // tower 0 (1 hop) -> C768 cols [0,256)
    hg(gsh, gsl, HD, nullptr, nullptr, 0, 0, g1h, g1l, HD, ginb1,
       nullptr, msh, msl, HD, NN, HD, HD, 1);
    hg(msh, msl, HD, nullptr, nullptr, 0, 0, g2h, g2l, HD, ginb2,
       nullptr, c768h, c768l, 768, NN, HD, HD, 0);
    // tower 1 hop 1 -> t1 (h1 slot)
    hg(gsh, gsl, HD, nullptr, nullptr, 0, 0, g1h + 65536, g1l + 65536, HD, ginb1 + 256,
       nullptr, msh, msl, HD, NN, HD, HD, 1);
    hg(msh, msl, HD, nullptr, nullptr, 0, 0, g2h + 65536, g2l + 65536, HD, ginb2 + 256,
       h1, nullptr, nullptr, HD, NN, HD, HD, 0);
    // tower 2 hop 1 -> t2 (h2 slot; h2 dead after gsh computed)
    hg(gsh, gsl, HD, nullptr, nullptr, 0, 0, g1h + 131072, g1l + 131072, HD, ginb1 + 512,
       nullptr, msh, msl, HD, NN, HD, HD, 1);
    hg(msh, msl, HD, nullptr, nullptr, 0, 0, g2h + 131072, g2l + 131072, HD, ginb2 + 512,
       h2, nullptr, nullptr, HD, NN, HD, HD, 0);
    // tower 1 hop 2 -> C768 cols [256,512)
    segsum_split_kernel<HD><<<NN, 256, 0, stream>>>(row_ptr, gsrc, h1, gsh, gsl, 1);
    hg(gsh, gsl, HD, nullptr, nullptr, 0, 0, g1h + 65536, g1l + 65536, HD, ginb1 + 256,
       nullptr, msh, msl, HD, NN, HD, HD, 1);
    hg(msh, msl, HD, nullptr, nullptr, 0, 0, g2h + 65536, g2l + 65536, HD, ginb2 + 256,
       nullptr, c768h + 256, c768l + 256, 768, NN, HD, HD, 0);
    // tower 2 hop 2 -> t2b (h1 slot)
    segsum_split_kernel<HD><<<NN, 256, 0, stream>>>(row_ptr, gsrc, h2, gsh, gsl, 1);
    hg(gsh, gsl, HD, nullptr, nullptr, 0, 0, g1h + 131072, g1l + 131072, HD, ginb1 + 512,
       nullptr, msh, msl, HD, NN, HD, HD, 1);
    hg(msh, msl, HD, nullptr, nullptr, 0, 0, g2h + 131072, g2l + 131072, HD, ginb2 + 512,
       h1, nullptr, nullptr, HD, NN, HD, HD, 0);
    // tower 2 hop 3 -> C768 cols [512,768)
    segsum_split_kernel<HD><<<NN, 256, 0, stream>>>(row_ptr, gsrc, h1, gsh, gsl, 1);
    hg(gsh, gsl, HD, nullptr, nullptr, 0, 0, g1h + 131072, g1l + 131072, HD, ginb1 + 512,
       nullptr, msh, msl, HD, NN, HD, HD, 1);
    hg(msh, msl, HD, nullptr, nullptr, 0, 0, g2h + 131072, g2l + 131072, HD, ginb2 + 512,
       nullptr, c768h + 512, c768l + 512, 768, NN, HD, HD, 0);

    // ------------------------------ mix + hh -------------------------------
    hg(c768h, c768l, 768, nullptr, nullptr, 0, 0, pjh, pjl, 768, projb,
       hh, shh_, shl_, HD, NN, HD, 768, 0);
    hhtail_kernel<<<1, 256, 0, stream>>>(rcinit, sinit, hh, shh_, shl_);

    // ------------------------------ gate / skip-sum / sGRU -----------------
    hg(shh_, shl_, HD, nullptr, nullptr, 0, 0, gwh, gwl, HD, gateb1,
       g1, nullptr, nullptr, 128, NN, 128, HD, 1);
    alpha_kernel<<<NN / 4, 256, 0, stream>>>(g1, gatew2, gateb2, rcmask, coef, NN);
    hipMemsetAsync(wsum, 0, 256 * 4, stream);
    colsum_kernel<<<64, 256, 0, stream>>>(hh, coef, wsum, NN, 128);
    sgru_kernel<<<1, 256, 0, stream>>>(wsum, rcinit, sinit, skipW, swih, swhh, sbih, sbhh,
                                       hh, shh_, shl_);

    // ------------------------------ attention row --------------------------
    hg(shh_, shl_, HD, nullptr, nullptr, 0, 0, kwh, kwl, HD, kb,
       k_all, nullptr, nullptr, HD, NHH, HD, HD, 0);
    hg(shh_, shl_, HD, nullptr, nullptr, 0, 0, vwh, vwl, HD, vb,
       v_all, nullptr, nullptr, HD, NHH, HD, HD, 0);
    qrow_kernel<<<1, 256, 0, stream>>>(hh, qw, qb, qrow);
    logits_kernel<<<(NHH + 3) / 4, 256, 0, stream>>>(k_all, qrow, logits, NHH);
    softmax_prep_kernel<<<1, 1024, 0, stream>>>(logits, pbuf, scal, NHH);
    hipMemsetAsync(ctx, 0, 256 * 4, stream);
    colsum_kernel<<<(NHH + 127) / 128, 256, 0, stream>>>(v_all, pbuf, ctx, NHH, 128);
    final_kernel<<<1, 256, 0, stream>>>(hh, ow, ob, ctx, scal, (float*)d_out);
}

// Round 4
// 887.001 us; speedup vs baseline: 1.6306x; 1.1505x over previous
//
#include <hip/hip_runtime.h>
#include <hip/hip_bf16.h>

#define NN   8192
#define NE   262144
#define HD   256
#define NHH  8194   // hh rows = N + 2

using f32x4  = __attribute__((ext_vector_type(4))) float;
using bf16x8 = __attribute__((ext_vector_type(8))) short;
typedef unsigned short u16;

__device__ __forceinline__ u16 f2bf(float f) {
    unsigned u = __builtin_bit_cast(unsigned, f);
    u = (u + 0x7FFFu + ((u >> 16) & 1u)) >> 16;
    return (u16)u;
}
__device__ __forceinline__ float bf2f(u16 h) {
    return __builtin_bit_cast(float, (unsigned)h << 16);
}
__device__ __forceinline__ void split1(float a, u16& h, u16& l) {
    h = f2bf(a);
    l = f2bf(a - bf2f(h));   // a - hi is exact in fp32
}
__device__ __forceinline__ void store_split4(u16* hi, u16* lo, size_t off, float4 v) {
    ushort4 h, l;
    split1(v.x, h.x, l.x); split1(v.y, h.y, l.y);
    split1(v.z, h.z, l.z); split1(v.w, h.w, l.w);
    *(ushort4*)(hi + off) = h;
    *(ushort4*)(lo + off) = l;
}

// ---------------------------------------------------------------- CSR build
__global__ void hist_kernel(const int* __restrict__ dst, int* __restrict__ cnt, int E) {
    int e = blockIdx.x * blockDim.x + threadIdx.x;
    if (e < E) atomicAdd(&cnt[dst[e]], 1);
}

__global__ __launch_bounds__(1024) void scan_kernel(const int* __restrict__ cnt, int* __restrict__ row_ptr) {
    __shared__ int sdata[1024];
    int tid = threadIdx.x;
    int v[8], local[8];
    int s = 0;
#pragma unroll
    for (int i = 0; i < 8; i++) v[i] = cnt[tid * 8 + i];
#pragma unroll
    for (int i = 0; i < 8; i++) { local[i] = s; s += v[i]; }
    sdata[tid] = s;
    __syncthreads();
    for (int off = 1; off < 1024; off <<= 1) {
        int t = (tid >= off) ? sdata[tid - off] : 0;
        __syncthreads();
        sdata[tid] += t;
        __syncthreads();
    }
    int base = (tid == 0) ? 0 : sdata[tid - 1];
#pragma unroll
    for (int i = 0; i < 8; i++) row_ptr[tid * 8 + i] = base + local[i];
    if (tid == 1023) row_ptr[8192] = sdata[1023];
}

__global__ void copy_int_kernel(const int* __restrict__ a, int* __restrict__ b, int n) {
    int i = blockIdx.x * blockDim.x + threadIdx.x;
    if (i < n) b[i] = a[i];
}

__global__ void fill_kernel(const int* __restrict__ dst, const int* __restrict__ src,
                            int* __restrict__ cursor, int* __restrict__ eids,
                            int* __restrict__ gsrc, int E) {
    int e = blockIdx.x * blockDim.x + threadIdx.x;
    if (e < E) {
        int pos = atomicAdd(&cursor[dst[e]], 1);
        eids[pos] = e;
        gsrc[pos] = src[e];
    }
}

// ---------------------------------------------- fused fp32 -> bf16x2 splits
struct SplitArgs {
    const float* src[13];
    u16* hi[13];
    u16* lo[13];
    int  off[14];   // cumulative block offsets (1024 elems per block)
};
__global__ __launch_bounds__(256) void multisplit_kernel(SplitArgs a) {
    int blk = blockIdx.x;
    int s = 0;
#pragma unroll
    for (int t = 0; t < 13; ++t) if (blk >= a.off[t + 1]) s = t + 1;
    size_t i = ((size_t)(blk - a.off[s]) * 256 + threadIdx.x) * 4;
    float4 v = *(const float4*)(a.src[s] + i);
    store_split4(a.hi[s], a.lo[s], i, v);
}

// --------------------------------------- segment sum -> split bf16 planes
// 64-feat variant (edge_attr): 16 slots x 16 threads, 2-deep.
__global__ __launch_bounds__(256) void segsum64_split_kernel(const int* __restrict__ row_ptr,
                                                             const int* __restrict__ idx,
                                                             const float* __restrict__ T,
                                                             u16* __restrict__ outh,
                                                             u16* __restrict__ outl) {
    __shared__ float4 part[15][16];
    const int n    = blockIdx.x;
    const int slot = threadIdx.x >> 4;
    const int fl   = threadIdx.x & 15;
    const int b = row_ptr[n], e = row_ptr[n + 1];
    float4 a0 = make_float4(0.f, 0.f, 0.f, 0.f);
    float4 a1 = make_float4(0.f, 0.f, 0.f, 0.f);
    int i = b + slot;
    for (; i + 16 < e; i += 32) {
        int s0 = idx[i], s1 = idx[i + 16];
        float4 v0 = *(const float4*)(T + (size_t)s0 * 64 + fl * 4);
        float4 v1 = *(const float4*)(T + (size_t)s1 * 64 + fl * 4);
        a0.x += v0.x; a0.y += v0.y; a0.z += v0.z; a0.w += v0.w;
        a1.x += v1.x; a1.y += v1.y; a1.z += v1.z; a1.w += v1.w;
    }
    if (i < e) {
        int s0 = idx[i];
        float4 v0 = *(const float4*)(T + (size_t)s0 * 64 + fl * 4);
        a0.x += v0.x; a0.y += v0.y; a0.z += v0.z; a0.w += v0.w;
    }
    a0.x += a1.x; a0.y += a1.y; a0.z += a1.z; a0.w += a1.w;
    if (slot > 0) part[slot - 1][fl] = a0;
    __syncthreads();
    if (slot == 0) {
#pragma unroll
        for (int t = 0; t < 15; ++t) {
            float4 p = part[t][fl];
            a0.x += p.x; a0.y += p.y; a0.z += p.z; a0.w += p.w;
        }
        store_split4(outh, outl, (size_t)n * 64 + fl * 4, a0);
    }
}

// 256-feat variant: 8 slots x 32 threads (8 floats/thread), 2-deep pipeline.
// out[n] = (self ? T[n] : 0) + sum_{i in [row_ptr[n],row_ptr[n+1])} T[idx[i]]
__global__ __launch_bounds__(256) void segsum256_split_kernel(const int* __restrict__ row_ptr,
                                                              const int* __restrict__ idx,
                                                              const float* __restrict__ T,
                                                              u16* __restrict__ outh,
                                                              u16* __restrict__ outl,
                                                              int self) {
    __shared__ float4 partA[7][32];
    __shared__ float4 partB[7][32];
    const int n    = blockIdx.x;
    const int slot = threadIdx.x >> 5;        // 0..7
    const int fl   = threadIdx.x & 31;        // floats [fl*8, fl*8+8)
    const int b = row_ptr[n], e = row_ptr[n + 1];
    float4 aA = make_float4(0.f, 0.f, 0.f, 0.f);
    float4 aB = make_float4(0.f, 0.f, 0.f, 0.f);
    float4 bA = make_float4(0.f, 0.f, 0.f, 0.f);
    float4 bB = make_float4(0.f, 0.f, 0.f, 0.f);
    int i = b + slot;
    for (; i + 8 < e; i += 16) {
        int s0 = idx[i], s1 = idx[i + 8];
        const float* p0 = T + (size_t)s0 * HD + fl * 8;
        const float* p1 = T + (size_t)s1 * HD + fl * 8;
        float4 v0a = *(const float4*)p0;
        float4 v0b = *(const float4*)(p0 + 4);
        float4 v1a = *(const float4*)p1;
        float4 v1b = *(const float4*)(p1 + 4);
        aA.x += v0a.x; aA.y += v0a.y; aA.z += v0a.z; aA.w += v0a.w;
        aB.x += v0b.x; aB.y += v0b.y; aB.z += v0b.z; aB.w += v0b.w;
        bA.x += v1a.x; bA.y += v1a.y; bA.z += v1a.z; bA.w += v1a.w;
        bB.x += v1b.x; bB.y += v1b.y; bB.z += v1b.z; bB.w += v1b.w;
    }
    if (i < e) {
        int s0 = idx[i];
        const float* p0 = T + (size_t)s0 * HD + fl * 8;
        float4 v0a = *(const float4*)p0;
        float4 v0b = *(const float4*)(p0 + 4);
        aA.x += v0a.x; aA.y += v0a.y; aA.z += v0a.z; aA.w += v0a.w;
        aB.x += v0b.x; aB.y += v0b.y; aB.z += v0b.z; aB.w += v0b.w;
    }
    aA.x += bA.x; aA.y += bA.y; aA.z += bA.z; aA.w += bA.w;
    aB.x += bB.x; aB.y += bB.y; aB.z += bB.z; aB.w += bB.w;
    if (slot > 0) { partA[slot - 1][fl] = aA; partB[slot - 1][fl] = aB; }
    __syncthreads();
    if (slot == 0) {
#pragma unroll
        for (int t = 0; t < 7; ++t) {
            float4 pa = partA[t][fl], pb = partB[t][fl];
            aA.x += pa.x; aA.y += pa.y; aA.z += pa.z; aA.w += pa.w;
            aB.x += pb.x; aB.y += pb.y; aB.z += pb.z; aB.w += pb.w;
        }
        if (self) {
            const float* ps = T + (size_t)n * HD + fl * 8;
            float4 sa = *(const float4*)ps;
            float4 sb = *(const float4*)(ps + 4);
            aA.x += sa.x; aA.y += sa.y; aA.z += sa.z; aA.w += sa.w;
            aB.x += sb.x; aB.y += sb.y; aB.z += sb.z; aB.w += sb.w;
        }
        store_split4(outh, outl, (size_t)n * HD + fl * 8, aA);
        store_split4(outh, outl, (size_t)n * HD + fl * 8 + 4, aB);
    }
}

// --------------------------------- split-bf16 3-product MFMA GEMM
// C[M x N] = act( (A ‖ Ab) @ W^T + bias ),  A = Ah + Al (bf16 planes), same W.
// C (fp32) and/or Chi/Clo (split planes) written. flags: 1 = relu.
// Block: 128 rows x 64 cols, 4 waves of 64x32. mfma_f32_16x16x32_bf16.
__global__ __launch_bounds__(256) void hgemm_kernel(
    const u16* __restrict__ Ah, const u16* __restrict__ Al, int lda,
    const u16* __restrict__ Abh, const u16* __restrict__ Abl, int ldab, int Kb,
    const u16* __restrict__ Wh, const u16* __restrict__ Wl, int ldw,
    const float* __restrict__ bias,
    float* __restrict__ C, u16* __restrict__ Chi, u16* __restrict__ Clo, int ldc,
    int M, int K, int flags) {
    const int tid  = threadIdx.x;
    const int wid  = tid >> 6;
    const int lane = tid & 63;
    const int lrow = lane & 15;
    const int koff = (lane >> 4) * 8;
    const int wrow0 = blockIdx.y * 128 + (wid >> 1) * 64;
    const int wcol0 = blockIdx.x * 64 + (wid & 1) * 32;

    f32x4 acc[4][2] = {};
    int rr[4];
#pragma unroll
    for (int fi = 0; fi < 4; ++fi) {
        int r = wrow0 + fi * 16 + lrow;
        rr[fi] = (r < M) ? r : (M - 1);     // clamp reads; stores guarded
    }

    for (int k0 = 0; k0 < K; k0 += 32) {
        bf16x8 ah[4], al[4], wh[2], wl[2];
#pragma unroll
        for (int ci = 0; ci < 2; ++ci) {
            size_t o = (size_t)(wcol0 + ci * 16 + lrow) * ldw + k0 + koff;
            wh[ci] = *(const bf16x8*)(Wh + o);
            wl[ci] = *(const bf16x8*)(Wl + o);
        }
#pragma unroll
        for (int fi = 0; fi < 4; ++fi) {
            size_t o = (size_t)rr[fi] * lda + k0 + koff;
            ah[fi] = *(const bf16x8*)(Ah + o);
            al[fi] = *(const bf16x8*)(Al + o);
        }
#pragma unroll
        for (int fi = 0; fi < 4; ++fi)
#pragma unroll
            for (int ci = 0; ci < 2; ++ci) {
                acc[fi][ci] = __builtin_amdgcn_mfma_f32_16x16x32_bf16(ah[fi], wh[ci], acc[fi][ci], 0, 0, 0);
                acc[fi][ci] = __builtin_amdgcn_mfma_f32_16x16x32_bf16(ah[fi], wl[ci], acc[fi][ci], 0, 0, 0);
                acc[fi][ci] = __builtin_amdgcn_mfma_f32_16x16x32_bf16(al[fi], wh[ci], acc[fi][ci], 0, 0, 0);
            }
    }

    if (Abh) {   // concat segment (edge-attr part of W_msg)
        const u16* W2h = Wh + K;
        const u16* W2l = Wl + K;
        for (int k0 = 0; k0 < Kb; k0 += 32) {
            bf16x8 ah[4], al[4], wh[2], wl[2];
#pragma unroll
            for (int ci = 0; ci < 2; ++ci) {
                size_t o = (size_t)(wcol0 + ci * 16 + lrow) * ldw + k0 + koff;
                wh[ci] = *(const bf16x8*)(W2h + o);
                wl[ci] = *(const bf16x8*)(W2l + o);
            }
#pragma unroll
            for (int fi = 0; fi < 4; ++fi) {
                size_t o = (size_t)rr[fi] * ldab + k0 + koff;
                ah[fi] = *(const bf16x8*)(Abh + o);
                al[fi] = *(const bf16x8*)(Abl + o);
            }
#pragma unroll
            for (int fi = 0; fi < 4; ++fi)
#pragma unroll
                for (int ci = 0; ci < 2; ++ci) {
                    acc[fi][ci] = __builtin_amdgcn_mfma_f32_16x16x32_bf16(ah[fi], wh[ci], acc[fi][ci], 0, 0, 0);
                    acc[fi][ci] = __builtin_amdgcn_mfma_f32_16x16x32_bf16(ah[fi], wl[ci], acc[fi][ci], 0, 0, 0);
                    acc[fi][ci] = __builtin_amdgcn_mfma_f32_16x16x32_bf16(al[fi], wh[ci], acc[fi][ci], 0, 0, 0);
                }
        }
    }

#pragma unroll
    for (int fi = 0; fi < 4; ++fi) {
        int rbase = wrow0 + fi * 16 + (lane >> 4) * 4;
#pragma unroll
        for (int ci = 0; ci < 2; ++ci) {
            int col = wcol0 + ci * 16 + lrow;
#pragma unroll
            for (int j = 0; j < 4; ++j) {
                int r = rbase + j;
                if (r >= M) continue;
                float v = acc[fi][ci][j];
                if (bias)      v += bias[col];
                if (flags & 1) v = fmaxf(v, 0.f);
                size_t o = (size_t)r * ldc + col;
                if (C) C[o] = v;
                if (Chi) { u16 hb, lb; split1(v, hb, lb); Chi[o] = hb; Clo[o] = lb; }
            }
        }
    }
}

// ----------------------------------------------------------- GRU elementwise
__global__ void gru_combine_kernel(const float* __restrict__ gi, const float* __restrict__ gh,
                                   const float* __restrict__ hprev, float* __restrict__ hout,
                                   u16* __restrict__ hhi, u16* __restrict__ hlo, int total4) {
    int t = blockIdx.x * 256 + threadIdx.x;
    if (t >= total4) return;
    int i4  = t * 4;
    int row = i4 >> 8, f = i4 & 255;
    size_t b = (size_t)row * 768;
    float4 ir = *(const float4*)(gi + b + f);
    float4 iz = *(const float4*)(gi + b + 256 + f);
    float4 in_ = *(const float4*)(gi + b + 512 + f);
    float4 hr = *(const float4*)(gh + b + f);
    float4 hz = *(const float4*)(gh + b + 256 + f);
    float4 hn = *(const float4*)(gh + b + 512 + f);
    float4 hp = *(const float4*)(hprev + (size_t)row * HD + f);
    float4 hv;
#pragma unroll
    for (int j = 0; j < 4; ++j) {
        float irj = ((const float*)&ir)[j], izj = ((const float*)&iz)[j], inj = ((const float*)&in_)[j];
        float hrj = ((const float*)&hr)[j], hzj = ((const float*)&hz)[j], hnj = ((const float*)&hn)[j];
        float r = 1.f / (1.f + expf(-(irj + hrj)));
        float z = 1.f / (1.f + expf(-(izj + hzj)));
        float n = tanhf(inj + r * hnj);
        ((float*)&hv)[j] = (1.f - z) * n + z * ((const float*)&hp)[j];
    }
    size_t o = (size_t)row * HD + f;
    *(float4*)(hout + o) = hv;
    if (hhi) store_split4(hhi, hlo, o, hv);
}

// ------------------------------------------------------------------ epilogue
__global__ void hhtail_kernel(const float* __restrict__ rc, const float* __restrict__ si,
                              float* __restrict__ hh, u16* __restrict__ hhi, u16* __restrict__ hlo) {
    int f = threadIdx.x;
    size_t o1 = (size_t)NN * HD + f, o2 = (size_t)(NN + 1) * HD + f;
    float a = rc[f], b = si[f];
    hh[o1] = a; hh[o2] = b;
    u16 h, l;
    split1(a, h, l); hhi[o1] = h; hlo[o1] = l;
    split1(b, h, l); hhi[o2] = h; hlo[o2] = l;
}

__global__ __launch_bounds__(256) void alpha_kernel(const float* __restrict__ g1, const float* __restrict__ gw2,
                                                    const float* __restrict__ gb2, const int* __restrict__ rcmask,
                                                    float* __restrict__ coef, int N) {
    int node = blockIdx.x * 4 + (threadIdx.x >> 6);
    int lane = threadIdx.x & 63;
    if (node >= N) return;
    float part = g1[(size_t)node * 128 + lane] * gw2[lane]
               + g1[(size_t)node * 128 + 64 + lane] * gw2[64 + lane];
    for (int off = 32; off > 0; off >>= 1) part += __shfl_down(part, off);
    if (lane == 0) {
        float a = 1.f / (1.f + expf(-(part + gb2[0])));
        coef[node] = rcmask[node] ? 0.f : a;
    }
}

__global__ __launch_bounds__(256) void colsum_kernel(const float* __restrict__ X, const float* __restrict__ coef,
                                                     float* __restrict__ out, int rows_total, int rows_per_blk) {
    int f  = threadIdx.x;
    int r0 = blockIdx.x * rows_per_blk;
    int r1 = r0 + rows_per_blk; if (r1 > rows_total) r1 = rows_total;
    float a0 = 0.f, a1 = 0.f;
    int r = r0;
    for (; r + 1 < r1; r += 2) {
        a0 += coef[r]     * X[(size_t)r * HD + f];
        a1 += coef[r + 1] * X[(size_t)(r + 1) * HD + f];
    }
    if (r < r1) a0 += coef[r] * X[(size_t)r * HD + f];
    atomicAdd(&out[f], a0 + a1);
}

// ------------------- parallel GEMV: out[r] = [bias[r]+] M[r,:256]·(vA [+vB])
__global__ __launch_bounds__(256) void gemv256_kernel(const float* __restrict__ M,
                                                      const float* __restrict__ vA,
                                                      const float* __restrict__ vB,
                                                      const float* __restrict__ bias,
                                                      float* __restrict__ out, int R) {
    int row  = blockIdx.x * 4 + (threadIdx.x >> 6);
    int lane = threadIdx.x & 63;
    if (row >= R) return;
    float4 v = *(const float4*)(vA + lane * 4);
    if (vB) {
        float4 b = *(const float4*)(vB + lane * 4);
        v.x += b.x; v.y += b.y; v.z += b.z; v.w += b.w;
    }
    float4 m = *(const float4*)(M + (size_t)row * 256 + lane * 4);
    float p = m.x * v.x + m.y * v.y + m.z * v.z + m.w * v.w;
    for (int off = 32; off > 0; off >>= 1) p += __shfl_down(p, off);
    if (lane == 0) out[row] = p + (bias ? bias[row] : 0.f);
}

__global__ void sgru_combine_kernel(const float* __restrict__ gi3, const float* __restrict__ gh3,
                                    const float* __restrict__ sinit,
                                    float* __restrict__ hh, u16* __restrict__ hhi, u16* __restrict__ hlo) {
    int f = threadIdx.x;
    float gir = gi3[f], giz = gi3[256 + f], gin_ = gi3[512 + f];
    float ghr = gh3[f], ghz = gh3[256 + f], ghn  = gh3[512 + f];
    float r = 1.f / (1.f + expf(-(gir + ghr)));
    float z = 1.f / (1.f + expf(-(giz + ghz)));
    float n = tanhf(gin_ + r * ghn);
    float hv = (1.f - z) * n + z * sinit[f];
    size_t o = (size_t)(NN + 1) * HD + f;
    hh[o] = hv;
    u16 h, l; split1(hv, h, l); hhi[o] = h; hlo[o] = l;
}

__global__ __launch_bounds__(256) void logits_kernel(const float* __restrict__ kall, const float* __restrict__ qrow,
                                                     float* __restrict__ logits, int n) {
    int j    = blockIdx.x * 4 + (threadIdx.x >> 6);
    int lane = threadIdx.x & 63;
    if (j >= n) return;
    float4 q = *(const float4*)(qrow + lane * 4);
    float4 k = *(const float4*)(kall + (size_t)j * HD + lane * 4);
    float part = q.x * k.x + q.y * k.y + q.z * k.z + q.w * k.w;
    for (int off = 32; off > 0; off >>= 1) part += __shfl_down(part, off);
    if (lane == 0) logits[j] = part * 0.0625f;   // / sqrt(256)
}

__global__ __launch_bounds__(1024) void softmax_prep_kernel(const float* __restrict__ logits, float* __restrict__ p,
                                                            float* __restrict__ scal, int n) {
    __shared__ float sd[1024];
    int tid = threadIdx.x;
    float mx = -1e30f;
    for (int j = tid; j < n; j += 1024) mx = fmaxf(mx, logits[j]);
    sd[tid] = mx;
    __syncthreads();
    for (int off = 512; off > 0; off >>= 1) { if (tid < off) sd[tid] = fmaxf(sd[tid], sd[tid + off]); __syncthreads(); }
    float m = sd[0];
    __syncthreads();
    float s = 0.f;
    for (int j = tid; j < n; j += 1024) { float e = expf(logits[j] - m); p[j] = e; s += e; }
    sd[tid] = s;
    __syncthreads();
    for (int off = 512; off > 0; off >>= 1) { if (tid < off) sd[tid] += sd[tid + off]; __syncthreads(); }
    if (tid == 0) scal[0] = sd[0];
}

__global__ __launch_bounds__(256) void final_gemv_kernel(const float* __restrict__ hh,
                                                         const float* __restrict__ ow,
                                                         const float* __restrict__ ob,
                                                         const float* __restrict__ ctx,
                                                         const float* __restrict__ scal,
                                                         float* __restrict__ out) {
    int row  = blockIdx.x * 4 + (threadIdx.x >> 6);
    int lane = threadIdx.x & 63;
    float4 c = *(const float4*)(ctx + lane * 4);
    float4 m = *(const float4*)(ow + (size_t)row * 256 + lane * 4);
    float p = m.x * c.x + m.y * c.y + m.z * c.z + m.w * c.w;
    for (int off = 32; off > 0; off >>= 1) p += __shfl_down(p, off);
    if (lane == 0) {
        float val = hh[(size_t)(NN + 1) * HD + row] + p / scal[0] + ob[row];
        out[row] = fmaxf(val, 0.f);
    }
}

// ---------------------------------------------------------------------------
extern "C" void kernel_launch(void* const* d_in, const int* in_sizes, int n_in,
                              void* d_out, int out_size, void* d_ws, size_t ws_size,
                              hipStream_t stream) {
    const float* x      = (const float*)d_in[0];
    const int*   ei     = (const int*)  d_in[1];
    const float* eattr  = (const float*)d_in[2];
    const int*   rcmask = (const int*)  d_in[3];
    const float* Wmsg1  = (const float*)d_in[4];
    const float* wih1   = (const float*)d_in[5];
    const float* whh1   = (const float*)d_in[6];
    const float* bih1   = (const float*)d_in[7];
    const float* bhh1   = (const float*)d_in[8];
    const float* Wmsg2  = (const float*)d_in[9];
    const float* wih2   = (const float*)d_in[10];
    const float* whh2   = (const float*)d_in[11];
    const float* bih2   = (const float*)d_in[12];
    const float* bhh2   = (const float*)d_in[13];
    const float* ginw1  = (const float*)d_in[14];
    const float* ginb1  = (const float*)d_in[15];
    const float* ginw2  = (const float*)d_in[16];
    const float* ginb2  = (const float*)d_in[17];
    const float* projw  = (const float*)d_in[18];
    const float* projb  = (const float*)d_in[19];
    const float* qw     = (const float*)d_in[20];
    const float* qb     = (const float*)d_in[21];
    const float* kw     = (const float*)d_in[22];
    const float* kb     = (const float*)d_in[23];
    const float* vw     = (const float*)d_in[24];
    const float* vb     = (const float*)d_in[25];
    const float* ow     = (const float*)d_in[26];
    const float* ob     = (const float*)d_in[27];
    const float* gatew1 = (const float*)d_in[28];
    const float* gateb1 = (const float*)d_in[29];
    const float* gatew2 = (const float*)d_in[30];
    const float* gateb2 = (const float*)d_in[31];
    const float* skipW  = (const float*)d_in[32];
    const float* swih   = (const float*)d_in[33];
    const float* swhh   = (const float*)d_in[34];
    const float* sbih   = (const float*)d_in[35];
    const float* sbhh   = (const float*)d_in[36];
    const float* rcinit = (const float*)d_in[37];
    const float* sinit  = (const float*)d_in[38];

    const int* src = ei;
    const int* dst = ei + NE;

    // ---------------- workspace layout (~104 MB) ---------------------------
    char*  w   = (char*)d_ws;
    size_t off = 0;
    auto alloc = [&](size_t bytes) -> void* {
        void* p = w + off;
        off = (off + bytes + 255) & ~(size_t)255;
        return p;
    };
    int*   cnt     = (int*)alloc((size_t)NN * 4);
    int*   row_ptr = (int*)alloc((size_t)(NN + 1) * 4);
    int*   eids    = (int*)alloc((size_t)NE * 4);
    int*   gsrc    = (int*)alloc((size_t)NE * 4);
    u16*   aeh     = (u16*)alloc((size_t)NN * 64 * 2);     // aggE split
    u16*   ael     = (u16*)alloc((size_t)NN * 64 * 2);
    u16*   shh_    = (u16*)alloc((size_t)NHH * HD * 2);    // shared: x-split / h1-split / hh-split
    u16*   shl_    = (u16*)alloc((size_t)NHH * HD * 2);
    u16*   gsh     = (u16*)alloc((size_t)NN * HD * 2);     // aggX / (t+agg) split
    u16*   gsl     = (u16*)alloc((size_t)NN * HD * 2);
    u16*   msh     = (u16*)alloc((size_t)NN * HD * 2);     // m / u split
    u16*   msl     = (u16*)alloc((size_t)NN * HD * 2);
    float* h1      = (float*)alloc((size_t)NN * HD * 4);   // h1 / t1 / t2b fp32
    float* h2      = (float*)alloc((size_t)NN * HD * 4);   // h2 / t2 fp32
    float* gi      = (float*)alloc((size_t)NN * 768 * 4);  // phase B: C768 split planes
    float* gh      = (float*)alloc((size_t)NN * 768 * 4);  // phase B: k_all, v_all, g1
    float* hh      = (float*)alloc((size_t)NHH * HD * 4);
    float* coef    = (float*)alloc((size_t)NN * 4);
    float* wsum    = (float*)alloc(256 * 4);
    float* qrow    = (float*)alloc(256 * 4);
    float* logits  = (float*)alloc((size_t)NHH * 4);
    float* pbuf    = (float*)alloc((size_t)NHH * 4);
    float* scal    = (float*)alloc(256);
    float* ctx     = (float*)alloc(256 * 4);
    float* mvec    = (float*)alloc(256 * 4);
    float* gi3     = (float*)alloc(768 * 4);
    float* gh3     = (float*)alloc(768 * 4);

    // weight split planes
    auto walloc = [&](size_t nel, u16** h, u16** l) {
        *h = (u16*)alloc(nel * 2); *l = (u16*)alloc(nel * 2);
    };
    u16 *xh, *xl;   // x split lives in shh_ (aliased use), but keep separate names below
    u16 *wm1h, *wm1l, *wm2h, *wm2l, *wi1h, *wi1l, *wh1h, *wh1l, *wi2h, *wi2l, *wh2h, *wh2l;
    u16 *g1h, *g1l, *g2h, *g2l, *pjh, *pjl, *gwh, *gwl, *kwh, *kwl, *vwh, *vwl;
    walloc(81920, &wm1h, &wm1l);   walloc(81920, &wm2h, &wm2l);
    walloc(196608, &wi1h, &wi1l);  walloc(196608, &wh1h, &wh1l);
    walloc(196608, &wi2h, &wi2l);  walloc(196608, &wh2h, &wh2l);
    walloc(196608, &g1h, &g1l);    walloc(196608, &g2h, &g2l);
    walloc(196608, &pjh, &pjl);    walloc(32768, &gwh, &gwl);
    walloc(65536, &kwh, &kwl);     walloc(65536, &vwh, &vwl);
    xh = shh_; xl = shl_;

    // phase-B aliases
    u16*   c768h = (u16*)gi;
    u16*   c768l = c768h + (size_t)NN * 768;
    float* k_all = gh;
    float* v_all = gh + (size_t)NHH * HD;
    float* g1    = gh + (size_t)2 * NHH * HD;

    auto hg = [&](const u16* Ah, const u16* Al, int lda,
                  const u16* Abh, const u16* Abl, int ldab, int Kb,
                  const u16* Wh, const u16* Wl, int ldw, const float* bias,
                  float* C, u16* Chi, u16* Clo, int ldc,
                  int M, int Nc, int K, int flags) {
        dim3 grid(Nc / 64, (M + 127) / 128);
        hgemm_kernel<<<grid, 256, 0, stream>>>(Ah, Al, lda, Abh, Abl, ldab, Kb,
                                               Wh, Wl, ldw, bias, C, Chi, Clo, ldc, M, K, flags);
    };

    // ------------------------------ CSR build ------------------------------
    hipMemsetAsync(cnt, 0, (size_t)NN * 4, stream);
    hist_kernel<<<NE / 256, 256, 0, stream>>>(dst, cnt, NE);
    scan_kernel<<<1, 1024, 0, stream>>>(cnt, row_ptr);
    copy_int_kernel<<<NN / 256, 256, 0, stream>>>(row_ptr, cnt, NN);
    fill_kernel<<<NE / 256, 256, 0, stream>>>(dst, src, cnt, eids, gsrc, NE);
    segsum64_split_kernel<<<NN, 256, 0, stream>>>(row_ptr, eids, eattr, aeh, ael);

    // ------------------------------ one-time splits (single launch) --------
    {
        SplitArgs a;
        const float* srcs[13] = { x, Wmsg1, Wmsg2, wih1, whh1, wih2, whh2,
                                  ginw1, ginw2, projw, gatew1, kw, vw };
        u16* his[13] = { xh, wm1h, wm2h, wi1h, wh1h, wi2h, wh2h, g1h, g2h, pjh, gwh, kwh, vwh };
        u16* los[13] = { xl, wm1l, wm2l, wi1l, wh1l, wi2l, wh2l, g1l, g2l, pjl, gwl, kwl, vwl };
        const int blocks[13] = { 2048, 80, 80, 192, 192, 192, 192, 192, 192, 192, 32, 64, 64 };
        int acc = 0;
        for (int t = 0; t < 13; ++t) { a.src[t] = srcs[t]; a.hi[t] = his[t]; a.lo[t] = los[t]; a.off[t] = acc; acc += blocks[t]; }
        a.off[13] = acc;
        multisplit_kernel<<<acc, 256, 0, stream>>>(a);
    }

    // ------------------------------ DMPNN 1 --------------------------------
    segsum256_split_kernel<<<NN, 256, 0, stream>>>(row_ptr, gsrc, x, gsh, gsl, 0);
    hg(gsh, gsl, HD, aeh, ael, 64, 64, wm1h, wm1l, 320, nullptr,
       nullptr, msh, msl, HD, NN, HD, HD, 0);
    hg(msh, msl, HD, nullptr, nullptr, 0, 0, wi1h, wi1l, HD, bih1,
       gi, nullptr, nullptr, 768, NN, 768, HD, 0);
    hg(shh_, shl_, HD, nullptr, nullptr, 0, 0, wh1h, wh1l, HD, bhh1,
       gh, nullptr, nullptr, 768, NN, 768, HD, 0);
    gru_combine_kernel<<<NN * HD / 1024, 256, 0, stream>>>(gi, gh, x, h1, shh_, shl_, NN * HD / 4);

    // ------------------------------ DMPNN 2 --------------------------------
    segsum256_split_kernel<<<NN, 256, 0, stream>>>(row_ptr, gsrc, h1, gsh, gsl, 0);
    hg(gsh, gsl, HD, aeh, ael, 64, 64, wm2h, wm2l, 320, nullptr,
       nullptr, msh, msl, HD, NN, HD, HD, 0);
    hg(msh, msl, HD, nullptr, nullptr, 0, 0, wi2h, wi2l, HD, bih2,
       gi, nullptr, nullptr, 768, NN, 768, HD, 0);
    hg(shh_, shl_, HD, nullptr, nullptr, 0, 0, wh2h, wh2l, HD, bhh2,
       gh, nullptr, nullptr, 768, NN, 768, HD, 0);
    gru_combine_kernel<<<NN * HD / 1024, 256, 0, stream>>>(gi, gh, h1, h2, nullptr, nullptr, NN * HD / 4);

    // ------------------------------ GIN towers -----------------------------
    segsum256_split_kernel<<<NN, 256, 0, stream>>>(row_ptr, gsrc, h2, gsh, gsl, 1);
    // tower 0 (1 hop) -> C768 cols [0,256)
    hg(gsh, gsl, HD, nullptr, nullptr, 0, 0, g1h, g1l, HD, ginb1,
       nullptr, msh, msl, HD, NN, HD, HD, 1);
    hg(msh, msl, HD, nullptr, nullptr, 0, 0, g2h, g2l, HD, ginb2,
       nullptr, c768h, c768l, 768, NN, HD, HD, 0);
    // tower 1 hop 1 -> t1 (h1 slot)
    hg(gsh, gsl, HD, nullptr, nullptr, 0, 0, g1h + 65536, g1l + 65536, HD, ginb1 + 256,
       nullptr, msh, msl, HD, NN, HD, HD, 1);
    hg(msh, msl, HD, nullptr, nullptr, 0, 0, g2h + 65536, g2l + 65536, HD, ginb2 + 256,
       h1, nullptr, nullptr, HD, NN, HD, HD, 0);
    // tower 2 hop 1 -> t2 (h2 slot)
    hg(gsh, gsl, HD, nullptr, nullptr, 0, 0, g1h + 131072, g1l + 131072, HD, ginb1 + 512,
       nullptr, msh, msl, HD, NN, HD, HD, 1);
    hg(msh, msl, HD, nullptr, nullptr, 0, 0, g2h + 131072, g2l + 131072, HD, ginb2 + 512,
       h2, nullptr, nullptr, HD, NN, HD, HD, 0);
    // tower 1 hop 2 -> C768 cols [256,512)
    segsum256_split_kernel<<<NN, 256, 0, stream>>>(row_ptr, gsrc, h1, gsh, gsl, 1);
    hg(gsh, gsl, HD, nullptr, nullptr, 0, 0, g1h + 65536, g1l + 65536, HD, ginb1 + 256,
       nullptr, msh, msl, HD, NN, HD, HD, 1);
    hg(msh, msl, HD, nullptr, nullptr, 0, 0, g2h + 65536, g2l + 65536, HD, ginb2 + 256,
       nullptr, c768h + 256, c768l + 256, 768, NN, HD, HD, 0);
    // tower 2 hop 2 -> t2b (h1 slot)
    segsum256_split_kernel<<<NN, 256, 0, stream>>>(row_ptr, gsrc, h2, gsh, gsl, 1);
    hg(gsh, gsl, HD, nullptr, nullptr, 0, 0, g1h + 131072, g1l + 131072, HD, ginb1 + 512,
       nullptr, msh, msl, HD, NN, HD, HD, 1);
    hg(msh, msl, HD, nullptr, nullptr, 0, 0, g2h + 131072, g2l + 131072, HD, ginb2 + 512,
       h1, nullptr, nullptr, HD, NN, HD, HD, 0);
    // tower 2 hop 3 -> C768 cols [512,768)
    segsum256_split_kernel<<<NN, 256, 0, stream>>>(row_ptr, gsrc, h1, gsh, gsl, 1);
    hg(gsh, gsl, HD, nullptr, nullptr, 0, 0, g1h + 131072, g1l + 131072, HD, ginb1 + 512,
       nullptr, msh, msl, HD, NN, HD, HD, 1);
    hg(msh, msl, HD, nullptr, nullptr, 0, 0, g2h + 131072, g2l + 131072, HD, ginb2 + 512,
       nullptr, c768h + 512, c768l + 512, 768, NN, HD, HD, 0);

    // ------------------------------ mix + hh -------------------------------
    hg(c768h, c768l, 768, nullptr, nullptr, 0, 0, pjh, pjl, 768, projb,
       hh, shh_, shl_, HD, NN, HD, 768, 0);
    hhtail_kernel<<<1, 256, 0, stream>>>(rcinit, sinit, hh, shh_, shl_);

    // ------------------------------ gate / skip-sum / sGRU -----------------
    hg(shh_, shl_, HD, nullptr, nullptr, 0, 0, gwh, gwl, HD, gateb1,
       g1, nullptr, nullptr, 128, NN, 128, HD, 1);
    alpha_kernel<<<NN / 4, 256, 0, stream>>>(g1, gatew2, gateb2, rcmask, coef, NN);
    hipMemsetAsync(wsum, 0, 256 * 4, stream);
    colsum_kernel<<<256, 256, 0, stream>>>(hh, coef, wsum, NN, 32);
    gemv256_kernel<<<64, 256, 0, stream>>>(skipW, wsum, rcinit, nullptr, mvec, 256);
    gemv256_kernel<<<192, 256, 0, stream>>>(swih, mvec, nullptr, sbih, gi3, 768);
    gemv256_kernel<<<192, 256, 0, stream>>>(swhh, sinit, nullptr, sbhh, gh3, 768);
    sgru_combine_kernel<<<1, 256, 0, stream>>>(gi3, gh3, sinit, hh, shh_, shl_);

    // ------------------------------ attention row --------------------------
    hg(shh_, shl_, HD, nullptr, nullptr, 0, 0, kwh, kwl, HD, kb,
       k_all, nullptr, nullptr, HD, NHH, HD, HD, 0);
    hg(shh_, shl_, HD, nullptr, nullptr, 0, 0, vwh, vwl, HD, vb,
       v_all, nullptr, nullptr, HD, NHH, HD, HD, 0);
    gemv256_kernel<<<64, 256, 0, stream>>>(qw, hh + (size_t)(NN + 1) * HD, nullptr, qb, qrow, 256);
    logits_kernel<<<(NHH + 3) / 4, 256, 0, stream>>>(k_all, qrow, logits, NHH);
    softmax_prep_kernel<<<1, 1024, 0, stream>>>(logits, pbuf, scal, NHH);
    hipMemsetAsync(ctx, 0, 256 * 4, stream);
    colsum_kernel<<<(NHH + 31) / 32, 256, 0, stream>>>(v_all, pbuf, ctx, NHH, 32);
    final_gemv_kernel<<<64, 256, 0, stream>>>(hh, ow, ob, ctx, scal, (float*)d_out);
}

// Round 5
// 811.622 us; speedup vs baseline: 1.7820x; 1.0929x over previous
//
#include <hip/hip_runtime.h>
#include <hip/hip_bf16.h>

#define NN   8192
#define NE   262144
#define HD   256
#define NHH  8194   // hh rows = N + 2

using f32x4  = __attribute__((ext_vector_type(4))) float;
using bf16x8 = __attribute__((ext_vector_type(8))) short;
typedef unsigned short u16;

__device__ __forceinline__ u16 f2bf(float f) {
    unsigned u = __builtin_bit_cast(unsigned, f);
    u = (u + 0x7FFFu + ((u >> 16) & 1u)) >> 16;
    return (u16)u;
}
__device__ __forceinline__ float bf2f(u16 h) {
    return __builtin_bit_cast(float, (unsigned)h << 16);
}
__device__ __forceinline__ void split1(float a, u16& h, u16& l) {
    h = f2bf(a);
    l = f2bf(a - bf2f(h));   // a - hi is exact in fp32
}
__device__ __forceinline__ void store_split4(u16* hi, u16* lo, size_t off, float4 v) {
    ushort4 h, l;
    split1(v.x, h.x, l.x); split1(v.y, h.y, l.y);
    split1(v.z, h.z, l.z); split1(v.w, h.w, l.w);
    *(ushort4*)(hi + off) = h;
    *(ushort4*)(lo + off) = l;
}

// bijective XCD-aware swizzle (m204): dispatch idx -> logical (bx,by),
// consecutive logical ids within an XCD chunk share `by` (A-row tile reuse).
__device__ __forceinline__ void swz_xy(int nbx, int& bx, int& by) {
    int nwg = gridDim.x;
    int o = blockIdx.x;
    int q = nwg >> 3, r = nwg & 7;
    int xcd = o & 7;
    int base = (xcd < r) ? xcd * (q + 1) : r * (q + 1) + (xcd - r) * q;
    int wg = base + (o >> 3);
    bx = wg % nbx;
    by = wg / nbx;
}

// ---------------------------------------------------------------- CSR build
__global__ void hist_kernel(const int* __restrict__ dst, int* __restrict__ cnt, int E) {
    int e = blockIdx.x * blockDim.x + threadIdx.x;
    if (e < E) atomicAdd(&cnt[dst[e]], 1);
}

__global__ __launch_bounds__(1024) void scan_kernel(const int* __restrict__ cnt, int* __restrict__ row_ptr) {
    __shared__ int sdata[1024];
    int tid = threadIdx.x;
    int v[8], local[8];
    int s = 0;
#pragma unroll
    for (int i = 0; i < 8; i++) v[i] = cnt[tid * 8 + i];
#pragma unroll
    for (int i = 0; i < 8; i++) { local[i] = s; s += v[i]; }
    sdata[tid] = s;
    __syncthreads();
    for (int off = 1; off < 1024; off <<= 1) {
        int t = (tid >= off) ? sdata[tid - off] : 0;
        __syncthreads();
        sdata[tid] += t;
        __syncthreads();
    }
    int base = (tid == 0) ? 0 : sdata[tid - 1];
#pragma unroll
    for (int i = 0; i < 8; i++) row_ptr[tid * 8 + i] = base + local[i];
    if (tid == 1023) row_ptr[8192] = sdata[1023];
}

__global__ void copy_int_kernel(const int* __restrict__ a, int* __restrict__ b, int n) {
    int i = blockIdx.x * blockDim.x + threadIdx.x;
    if (i < n) b[i] = a[i];
}

__global__ void fill_kernel(const int* __restrict__ dst, const int* __restrict__ src,
                            int* __restrict__ cursor, int* __restrict__ eids,
                            int* __restrict__ gsrc, int E) {
    int e = blockIdx.x * blockDim.x + threadIdx.x;
    if (e < E) {
        int pos = atomicAdd(&cursor[dst[e]], 1);
        eids[pos] = e;
        gsrc[pos] = src[e];
    }
}

// ---------------------------------------------- fused fp32 -> bf16x2 splits
struct SplitArgs {
    const float* src[13];
    u16* hi[13];
    u16* lo[13];
    int  off[14];   // cumulative block offsets (1024 elems per block)
};
__global__ __launch_bounds__(256) void multisplit_kernel(SplitArgs a) {
    int blk = blockIdx.x;
    int s = 0;
#pragma unroll
    for (int t = 0; t < 13; ++t) if (blk >= a.off[t + 1]) s = t + 1;
    size_t i = ((size_t)(blk - a.off[s]) * 256 + threadIdx.x) * 4;
    float4 v = *(const float4*)(a.src[s] + i);
    store_split4(a.hi[s], a.lo[s], i, v);
}

// --------------------------------------- segment sum -> split bf16 planes
// 64-feat variant (edge_attr): 16 slots x 16 threads, 2-deep.
__global__ __launch_bounds__(256) void segsum64_split_kernel(const int* __restrict__ row_ptr,
                                                             const int* __restrict__ idx,
                                                             const float* __restrict__ T,
                                                             u16* __restrict__ outh,
                                                             u16* __restrict__ outl) {
    __shared__ float4 part[15][16];
    const int n    = blockIdx.x;
    const int slot = threadIdx.x >> 4;
    const int fl   = threadIdx.x & 15;
    const int b = row_ptr[n], e = row_ptr[n + 1];
    float4 a0 = make_float4(0.f, 0.f, 0.f, 0.f);
    float4 a1 = make_float4(0.f, 0.f, 0.f, 0.f);
    int i = b + slot;
    for (; i + 16 < e; i += 32) {
        int s0 = idx[i], s1 = idx[i + 16];
        float4 v0 = *(const float4*)(T + (size_t)s0 * 64 + fl * 4);
        float4 v1 = *(const float4*)(T + (size_t)s1 * 64 + fl * 4);
        a0.x += v0.x; a0.y += v0.y; a0.z += v0.z; a0.w += v0.w;
        a1.x += v1.x; a1.y += v1.y; a1.z += v1.z; a1.w += v1.w;
    }
    if (i < e) {
        int s0 = idx[i];
        float4 v0 = *(const float4*)(T + (size_t)s0 * 64 + fl * 4);
        a0.x += v0.x; a0.y += v0.y; a0.z += v0.z; a0.w += v0.w;
    }
    a0.x += a1.x; a0.y += a1.y; a0.z += a1.z; a0.w += a1.w;
    if (slot > 0) part[slot - 1][fl] = a0;
    __syncthreads();
    if (slot == 0) {
#pragma unroll
        for (int t = 0; t < 15; ++t) {
            float4 p = part[t][fl];
            a0.x += p.x; a0.y += p.y; a0.z += p.z; a0.w += p.w;
        }
        store_split4(outh, outl, (size_t)n * 64 + fl * 4, a0);
    }
}

// 256-feat variant: 8 slots x 32 threads (8 floats/thread), 2-deep pipeline.
__global__ __launch_bounds__(256) void segsum256_split_kernel(const int* __restrict__ row_ptr,
                                                              const int* __restrict__ idx,
                                                              const float* __restrict__ T,
                                                              u16* __restrict__ outh,
                                                              u16* __restrict__ outl,
                                                              int self) {
    __shared__ float4 partA[7][32];
    __shared__ float4 partB[7][32];
    const int n    = blockIdx.x;
    const int slot = threadIdx.x >> 5;        // 0..7
    const int fl   = threadIdx.x & 31;        // floats [fl*8, fl*8+8)
    const int b = row_ptr[n], e = row_ptr[n + 1];
    float4 aA = make_float4(0.f, 0.f, 0.f, 0.f);
    float4 aB = make_float4(0.f, 0.f, 0.f, 0.f);
    float4 bA = make_float4(0.f, 0.f, 0.f, 0.f);
    float4 bB = make_float4(0.f, 0.f, 0.f, 0.f);
    int i = b + slot;
    for (; i + 8 < e; i += 16) {
        int s0 = idx[i], s1 = idx[i + 8];
        const float* p0 = T + (size_t)s0 * HD + fl * 8;
        const float* p1 = T + (size_t)s1 * HD + fl * 8;
        float4 v0a = *(const float4*)p0;
        float4 v0b = *(const float4*)(p0 + 4);
        float4 v1a = *(const float4*)p1;
        float4 v1b = *(const float4*)(p1 + 4);
        aA.x += v0a.x; aA.y += v0a.y; aA.z += v0a.z; aA.w += v0a.w;
        aB.x += v0b.x; aB.y += v0b.y; aB.z += v0b.z; aB.w += v0b.w;
        bA.x += v1a.x; bA.y += v1a.y; bA.z += v1a.z; bA.w += v1a.w;
        bB.x += v1b.x; bB.y += v1b.y; bB.z += v1b.z; bB.w += v1b.w;
    }
    if (i < e) {
        int s0 = idx[i];
        const float* p0 = T + (size_t)s0 * HD + fl * 8;
        float4 v0a = *(const float4*)p0;
        float4 v0b = *(const float4*)(p0 + 4);
        aA.x += v0a.x; aA.y += v0a.y; aA.z += v0a.z; aA.w += v0a.w;
        aB.x += v0b.x; aB.y += v0b.y; aB.z += v0b.z; aB.w += v0b.w;
    }
    aA.x += bA.x; aA.y += bA.y; aA.z += bA.z; aA.w += bA.w;
    aB.x += bB.x; aB.y += bB.y; aB.z += bB.z; aB.w += bB.w;
    if (slot > 0) { partA[slot - 1][fl] = aA; partB[slot - 1][fl] = aB; }
    __syncthreads();
    if (slot == 0) {
#pragma unroll
        for (int t = 0; t < 7; ++t) {
            float4 pa = partA[t][fl], pb = partB[t][fl];
            aA.x += pa.x; aA.y += pa.y; aA.z += pa.z; aA.w += pa.w;
            aB.x += pb.x; aB.y += pb.y; aB.z += pb.z; aB.w += pb.w;
        }
        if (self) {
            const float* ps = T + (size_t)n * HD + fl * 8;
            float4 sa = *(const float4*)ps;
            float4 sb = *(const float4*)(ps + 4);
            aA.x += sa.x; aA.y += sa.y; aA.z += sa.z; aA.w += sa.w;
            aB.x += sb.x; aB.y += sb.y; aB.z += sb.z; aB.w += sb.w;
        }
        store_split4(outh, outl, (size_t)n * HD + fl * 8, aA);
        store_split4(outh, outl, (size_t)n * HD + fl * 8 + 4, aB);
    }
}

// --------------------------------- split-bf16 3-product MFMA GEMM
// C[M x N] = act( (A ‖ Ab) @ W^T + bias ),  A = Ah + Al (bf16 planes).
// 1-D grid, XCD-swizzled. Block: 128 rows x 64 cols, 4 waves of 64x32.
__global__ __launch_bounds__(256) void hgemm_kernel(
    const u16* __restrict__ Ah, const u16* __restrict__ Al, int lda,
    const u16* __restrict__ Abh, const u16* __restrict__ Abl, int ldab, int Kb,
    const u16* __restrict__ Wh, const u16* __restrict__ Wl, int ldw,
    const float* __restrict__ bias,
    float* __restrict__ C, u16* __restrict__ Chi, u16* __restrict__ Clo, int ldc,
    int M, int K, int flags, int nbx) {
    int bx, by;
    swz_xy(nbx, bx, by);
    const int tid  = threadIdx.x;
    const int wid  = tid >> 6;
    const int lane = tid & 63;
    const int lrow = lane & 15;
    const int koff = (lane >> 4) * 8;
    const int wrow0 = by * 128 + (wid >> 1) * 64;
    const int wcol0 = bx * 64 + (wid & 1) * 32;

    f32x4 acc[4][2] = {};
    int rr[4];
#pragma unroll
    for (int fi = 0; fi < 4; ++fi) {
        int r = wrow0 + fi * 16 + lrow;
        rr[fi] = (r < M) ? r : (M - 1);     // clamp reads; stores guarded
    }

    for (int k0 = 0; k0 < K; k0 += 32) {
        bf16x8 ah[4], al[4], wh[2], wl[2];
#pragma unroll
        for (int ci = 0; ci < 2; ++ci) {
            size_t o = (size_t)(wcol0 + ci * 16 + lrow) * ldw + k0 + koff;
            wh[ci] = *(const bf16x8*)(Wh + o);
            wl[ci] = *(const bf16x8*)(Wl + o);
        }
#pragma unroll
        for (int fi = 0; fi < 4; ++fi) {
            size_t o = (size_t)rr[fi] * lda + k0 + koff;
            ah[fi] = *(const bf16x8*)(Ah + o);
            al[fi] = *(const bf16x8*)(Al + o);
        }
#pragma unroll
        for (int fi = 0; fi < 4; ++fi)
#pragma unroll
            for (int ci = 0; ci < 2; ++ci) {
                acc[fi][ci] = __builtin_amdgcn_mfma_f32_16x16x32_bf16(ah[fi], wh[ci], acc[fi][ci], 0, 0, 0);
                acc[fi][ci] = __builtin_amdgcn_mfma_f32_16x16x32_bf16(ah[fi], wl[ci], acc[fi][ci], 0, 0, 0);
                acc[fi][ci] = __builtin_amdgcn_mfma_f32_16x16x32_bf16(al[fi], wh[ci], acc[fi][ci], 0, 0, 0);
            }
    }

    if (Abh) {   // concat segment (edge-attr part of W_msg)
        const u16* W2h = Wh + K;
        const u16* W2l = Wl + K;
        for (int k0 = 0; k0 < Kb; k0 += 32) {
            bf16x8 ah[4], al[4], wh[2], wl[2];
#pragma unroll
            for (int ci = 0; ci < 2; ++ci) {
                size_t o = (size_t)(wcol0 + ci * 16 + lrow) * ldw + k0 + koff;
                wh[ci] = *(const bf16x8*)(W2h + o);
                wl[ci] = *(const bf16x8*)(W2l + o);
            }
#pragma unroll
            for (int fi = 0; fi < 4; ++fi) {
                size_t o = (size_t)rr[fi] * ldab + k0 + koff;
                ah[fi] = *(const bf16x8*)(Abh + o);
                al[fi] = *(const bf16x8*)(Abl + o);
            }
#pragma unroll
            for (int fi = 0; fi < 4; ++fi)
#pragma unroll
                for (int ci = 0; ci < 2; ++ci) {
                    acc[fi][ci] = __builtin_amdgcn_mfma_f32_16x16x32_bf16(ah[fi], wh[ci], acc[fi][ci], 0, 0, 0);
                    acc[fi][ci] = __builtin_amdgcn_mfma_f32_16x16x32_bf16(ah[fi], wl[ci], acc[fi][ci], 0, 0, 0);
                    acc[fi][ci] = __builtin_amdgcn_mfma_f32_16x16x32_bf16(al[fi], wh[ci], acc[fi][ci], 0, 0, 0);
                }
        }
    }

#pragma unroll
    for (int fi = 0; fi < 4; ++fi) {
        int rbase = wrow0 + fi * 16 + (lane >> 4) * 4;
#pragma unroll
        for (int ci = 0; ci < 2; ++ci) {
            int col = wcol0 + ci * 16 + lrow;
#pragma unroll
            for (int j = 0; j < 4; ++j) {
                int r = rbase + j;
                if (r >= M) continue;
                float v = acc[fi][ci][j];
                if (bias)      v += bias[col];
                if (flags & 1) v = fmaxf(v, 0.f);
                size_t o = (size_t)r * ldc + col;
                if (C) C[o] = v;
                if (Chi) { u16 hb, lb; split1(v, hb, lb); Chi[o] = hb; Clo[o] = lb; }
            }
        }
    }
}

// --------------------- fused GRU: 6 gate-GEMMs + nonlinearity in one kernel
// gi = m @ wih^T + bih ; gh = hprev @ whh^T + bhh ; h = (1-z)n + z*hprev
// Block: 64 rows x 64 fcols, 4 waves of 32x32. grid = 512 (fixed, NN rows).
__global__ __launch_bounds__(256, 2) void gru_fused_kernel(
    const u16* __restrict__ Mh, const u16* __restrict__ Ml,
    const u16* __restrict__ Hh, const u16* __restrict__ Hl,
    const float* __restrict__ Hprev,
    const u16* __restrict__ Wih_h, const u16* __restrict__ Wih_l,
    const u16* __restrict__ Whh_h, const u16* __restrict__ Whh_l,
    const float* __restrict__ bih, const float* __restrict__ bhh,
    float* __restrict__ Hout, u16* __restrict__ Ohi, u16* __restrict__ Olo) {
    int bx, by;
    swz_xy(4, bx, by);
    const int tid  = threadIdx.x;
    const int wid  = tid >> 6;
    const int lane = tid & 63;
    const int lrow = lane & 15;
    const int koff = (lane >> 4) * 8;
    const int row0  = by * 64 + (wid >> 1) * 32;
    const int fcol0 = bx * 64 + (wid & 1) * 32;

    f32x4 gacc[6][2][2] = {};   // [gi_r,gi_z,gi_n,gh_r,gh_z,gh_n][rowfrag][colfrag]

    for (int k0 = 0; k0 < 256; k0 += 32) {
        bf16x8 amh[2], aml[2], ahh[2], ahl[2];
#pragma unroll
        for (int fi = 0; fi < 2; ++fi) {
            size_t oa = (size_t)(row0 + fi * 16 + lrow) * HD + k0 + koff;
            amh[fi] = *(const bf16x8*)(Mh + oa);
            aml[fi] = *(const bf16x8*)(Ml + oa);
            ahh[fi] = *(const bf16x8*)(Hh + oa);
            ahl[fi] = *(const bf16x8*)(Hl + oa);
        }
#pragma unroll
        for (int g = 0; g < 3; ++g) {
            bf16x8 wh[2], wl[2];
#pragma unroll
            for (int ci = 0; ci < 2; ++ci) {
                size_t wo = (size_t)(g * 256 + fcol0 + ci * 16 + lrow) * HD + k0 + koff;
                wh[ci] = *(const bf16x8*)(Wih_h + wo);
                wl[ci] = *(const bf16x8*)(Wih_l + wo);
            }
#pragma unroll
            for (int fi = 0; fi < 2; ++fi)
#pragma unroll
                for (int ci = 0; ci < 2; ++ci) {
                    gacc[g][fi][ci] = __builtin_amdgcn_mfma_f32_16x16x32_bf16(amh[fi], wh[ci], gacc[g][fi][ci], 0, 0, 0);
                    gacc[g][fi][ci] = __builtin_amdgcn_mfma_f32_16x16x32_bf16(amh[fi], wl[ci], gacc[g][fi][ci], 0, 0, 0);
                    gacc[g][fi][ci] = __builtin_amdgcn_mfma_f32_16x16x32_bf16(aml[fi], wh[ci], gacc[g][fi][ci], 0, 0, 0);
                }
#pragma unroll
            for (int ci = 0; ci < 2; ++ci) {
                size_t wo = (size_t)(g * 256 + fcol0 + ci * 16 + lrow) * HD + k0 + koff;
                wh[ci] = *(const bf16x8*)(Whh_h + wo);
                wl[ci] = *(const bf16x8*)(Whh_l + wo);
            }
#pragma unroll
            for (int fi = 0; fi < 2; ++fi)
#pragma unroll
                for (int ci = 0; ci < 2; ++ci) {
                    gacc[3 + g][fi][ci] = __builtin_amdgcn_mfma_f32_16x16x32_bf16(ahh[fi], wh[ci], gacc[3 + g][fi][ci], 0, 0, 0);
                    gacc[3 + g][fi][ci] = __builtin_amdgcn_mfma_f32_16x16x32_bf16(ahh[fi], wl[ci], gacc[3 + g][fi][ci], 0, 0, 0);
                    gacc[3 + g][fi][ci] = __builtin_amdgcn_mfma_f32_16x16x32_bf16(ahl[fi], wh[ci], gacc[3 + g][fi][ci], 0, 0, 0);
                }
        }
    }

#pragma unroll
    for (int ci = 0; ci < 2; ++ci) {
        int f = fcol0 + ci * 16 + lrow;
        float bir = bih[f], biz = bih[256 + f], bin_ = bih[512 + f];
        float bhr = bhh[f], bhz = bhh[256 + f], bhn = bhh[512 + f];
#pragma unroll
        for (int fi = 0; fi < 2; ++fi) {
            int rbase = row0 + fi * 16 + (lane >> 4) * 4;
#pragma unroll
            for (int j = 0; j < 4; ++j) {
                int row = rbase + j;
                float gir  = gacc[0][fi][ci][j] + bir;
                float giz  = gacc[1][fi][ci][j] + biz;
                float gin_ = gacc[2][fi][ci][j] + bin_;
                float ghr  = gacc[3][fi][ci][j] + bhr;
                float ghz  = gacc[4][fi][ci][j] + bhz;
                float ghn  = gacc[5][fi][ci][j] + bhn;
                float r = 1.f / (1.f + expf(-(gir + ghr)));
                float z = 1.f / (1.f + expf(-(giz + ghz)));
                float n = tanhf(gin_ + r * ghn);
                size_t oo = (size_t)row * HD + f;
                float hv = (1.f - z) * n + z * Hprev[oo];
                Hout[oo] = hv;
                if (Ohi) { u16 hb, lb; split1(hv, hb, lb); Ohi[oo] = hb; Olo[oo] = lb; }
            }
        }
    }
}

// ------------------------------------------------------------------ epilogue
__global__ void hhtail_kernel(const float* __restrict__ rc, const float* __restrict__ si,
                              float* __restrict__ hh, u16* __restrict__ hhi, u16* __restrict__ hlo) {
    int f = threadIdx.x;
    size_t o1 = (size_t)NN * HD + f, o2 = (size_t)(NN + 1) * HD + f;
    float a = rc[f], b = si[f];
    hh[o1] = a; hh[o2] = b;
    u16 h, l;
    split1(a, h, l); hhi[o1] = h; hlo[o1] = l;
    split1(b, h, l); hhi[o2] = h; hlo[o2] = l;
}

__global__ __launch_bounds__(256) void alpha_kernel(const float* __restrict__ g1, const float* __restrict__ gw2,
                                                    const float* __restrict__ gb2, const int* __restrict__ rcmask,
                                                    float* __restrict__ coef, int N) {
    int node = blockIdx.x * 4 + (threadIdx.x >> 6);
    int lane = threadIdx.x & 63;
    if (node >= N) return;
    float part = g1[(size_t)node * 128 + lane] * gw2[lane]
               + g1[(size_t)node * 128 + 64 + lane] * gw2[64 + lane];
    for (int off = 32; off > 0; off >>= 1) part += __shfl_down(part, off);
    if (lane == 0) {
        float a = 1.f / (1.f + expf(-(part + gb2[0])));
        coef[node] = rcmask[node] ? 0.f : a;
    }
}

__global__ __launch_bounds__(256) void colsum_kernel(const float* __restrict__ X, const float* __restrict__ coef,
                                                     float* __restrict__ out, int rows_total, int rows_per_blk) {
    int f  = threadIdx.x;
    int r0 = blockIdx.x * rows_per_blk;
    int r1 = r0 + rows_per_blk; if (r1 > rows_total) r1 = rows_total;
    float a0 = 0.f, a1 = 0.f;
    int r = r0;
    for (; r + 1 < r1; r += 2) {
        a0 += coef[r]     * X[(size_t)r * HD + f];
        a1 += coef[r + 1] * X[(size_t)(r + 1) * HD + f];
    }
    if (r < r1) a0 += coef[r] * X[(size_t)r * HD + f];
    atomicAdd(&out[f], a0 + a1);
}

// ------------------- parallel GEMV: out[r] = [bias[r]+] M[r,:256]·(vA [+vB])
__global__ __launch_bounds__(256) void gemv256_kernel(const float* __restrict__ M,
                                                      const float* __restrict__ vA,
                                                      const float* __restrict__ vB,
                                                      const float* __restrict__ bias,
                                                      float* __restrict__ out, int R) {
    int row  = blockIdx.x * 4 + (threadIdx.x >> 6);
    int lane = threadIdx.x & 63;
    if (row >= R) return;
    float4 v = *(const float4*)(vA + lane * 4);
    if (vB) {
        float4 b = *(const float4*)(vB + lane * 4);
        v.x += b.x; v.y += b.y; v.z += b.z; v.w += b.w;
    }
    float4 m = *(const float4*)(M + (size_t)row * 256 + lane * 4);
    float p = m.x * v.x + m.y * v.y + m.z * v.z + m.w * v.w;
    for (int off = 32; off > 0; off >>= 1) p += __shfl_down(p, off);
    if (lane == 0) out[row] = p + (bias ? bias[row] : 0.f);
}

__global__ void sgru_combine_kernel(const float* __restrict__ gi3, const float* __restrict__ gh3,
                                    const float* __restrict__ sinit,
                                    float* __restrict__ hh, u16* __restrict__ hhi, u16* __restrict__ hlo) {
    int f = threadIdx.x;
    float gir = gi3[f], giz = gi3[256 + f], gin_ = gi3[512 + f];
    float ghr = gh3[f], ghz = gh3[256 + f], ghn  = gh3[512 + f];
    float r = 1.f / (1.f + expf(-(gir + ghr)));
    float z = 1.f / (1.f + expf(-(giz + ghz)));
    float n = tanhf(gin_ + r * ghn);
    float hv = (1.f - z) * n + z * sinit[f];
    size_t o = (size_t)(NN + 1) * HD + f;
    hh[o] = hv;
    u16 h, l; split1(hv, h, l); hhi[o] = h; hlo[o] = l;
}

__global__ __launch_bounds__(256) void logits_kernel(const float* __restrict__ kall, const float* __restrict__ qrow,
                                                     float* __restrict__ logits, int n) {
    int j    = blockIdx.x * 4 + (threadIdx.x >> 6);
    int lane = threadIdx.x & 63;
    if (j >= n) return;
    float4 q = *(const float4*)(qrow + lane * 4);
    float4 k = *(const float4*)(kall + (size_t)j * HD + lane * 4);
    float part = q.x * k.x + q.y * k.y + q.z * k.z + q.w * k.w;
    for (int off = 32; off > 0; off >>= 1) part += __shfl_down(part, off);
    if (lane == 0) logits[j] = part * 0.0625f;   // / sqrt(256)
}

__global__ __launch_bounds__(1024) void softmax_prep_kernel(const float* __restrict__ logits, float* __restrict__ p,
                                                            float* __restrict__ scal, int n) {
    __shared__ float sd[1024];
    int tid = threadIdx.x;
    float mx = -1e30f;
    for (int j = tid; j < n; j += 1024) mx = fmaxf(mx, logits[j]);
    sd[tid] = mx;
    __syncthreads();
    for (int off = 512; off > 0; off >>= 1) { if (tid < off) sd[tid] = fmaxf(sd[tid], sd[tid + off]); __syncthreads(); }
    float m = sd[0];
    __syncthreads();
    float s = 0.f;
    for (int j = tid; j < n; j += 1024) { float e = expf(logits[j] - m); p[j] = e; s += e; }
    sd[tid] = s;
    __syncthreads();
    for (int off = 512; off > 0; off >>= 1) { if (tid < off) sd[tid] += sd[tid + off]; __syncthreads(); }
    if (tid == 0) scal[0] = sd[0];
}

__global__ __launch_bounds__(256) void final_gemv_kernel(const float* __restrict__ hh,
                                                         const float* __restrict__ ow,
                                                         const float* __restrict__ ob,
                                                         const float* __restrict__ ctx,
                                                         const float* __restrict__ scal,
                                                         float* __restrict__ out) {
    int row  = blockIdx.x * 4 + (threadIdx.x >> 6);
    int lane = threadIdx.x & 63;
    float4 c = *(const float4*)(ctx + lane * 4);
    float4 m = *(const float4*)(ow + (size_t)row * 256 + lane * 4);
    float p = m.x * c.x + m.y * c.y + m.z * c.z + m.w * c.w;
    for (int off = 32; off > 0; off >>= 1) p += __shfl_down(p, off);
    if (lane == 0) {
        float val = hh[(size_t)(NN + 1) * HD + row] + p / scal[0] + ob[row];
        out[row] = fmaxf(val, 0.f);
    }
}

// ---------------------------------------------------------------------------
extern "C" void kernel_launch(void* const* d_in, const int* in_sizes, int n_in,
                              void* d_out, int out_size, void* d_ws, size_t ws_size,
                              hipStream_t stream) {
    const float* x      = (const float*)d_in[0];
    const int*   ei     = (const int*)  d_in[1];
    const float* eattr  = (const float*)d_in[2];
    const int*   rcmask = (const int*)  d_in[3];
    const float* Wmsg1  = (const float*)d_in[4];
    const float* wih1   = (const float*)d_in[5];
    const float* whh1   = (const float*)d_in[6];
    const float* bih1   = (const float*)d_in[7];
    const float* bhh1   = (const float*)d_in[8];
    const float* Wmsg2  = (const float*)d_in[9];
    const float* wih2   = (const float*)d_in[10];
    const float* whh2   = (const float*)d_in[11];
    const float* bih2   = (const float*)d_in[12];
    const float* bhh2   = (const float*)d_in[13];
    const float* ginw1  = (const float*)d_in[14];
    const float* ginb1  = (const float*)d_in[15];
    const float* ginw2  = (const float*)d_in[16];
    const float* ginb2  = (const float*)d_in[17];
    const float* projw  = (const float*)d_in[18];
    const float* projb  = (const float*)d_in[19];
    const float* qw     = (const float*)d_in[20];
    const float* qb     = (const float*)d_in[21];
    const float* kw     = (const float*)d_in[22];
    const float* kb     = (const float*)d_in[23];
    const float* vw     = (const float*)d_in[24];
    const float* vb     = (const float*)d_in[25];
    const float* ow     = (const float*)d_in[26];
    const float* ob     = (const float*)d_in[27];
    const float* gatew1 = (const float*)d_in[28];
    const float* gateb1 = (const float*)d_in[29];
    const float* gatew2 = (const float*)d_in[30];
    const float* gateb2 = (const float*)d_in[31];
    const float* skipW  = (const float*)d_in[32];
    const float* swih   = (const float*)d_in[33];
    const float* swhh   = (const float*)d_in[34];
    const float* sbih   = (const float*)d_in[35];
    const float* sbhh   = (const float*)d_in[36];
    const float* rcinit = (const float*)d_in[37];
    const float* sinit  = (const float*)d_in[38];

    const int* src = ei;
    const int* dst = ei + NE;

    // ---------------- workspace layout -------------------------------------
    char*  w   = (char*)d_ws;
    size_t off = 0;
    auto alloc = [&](size_t bytes) -> void* {
        void* p = w + off;
        off = (off + bytes + 255) & ~(size_t)255;
        return p;
    };
    int*   cnt     = (int*)alloc((size_t)NN * 4);
    int*   row_ptr = (int*)alloc((size_t)(NN + 1) * 4);
    int*   eids    = (int*)alloc((size_t)NE * 4);
    int*   gsrc    = (int*)alloc((size_t)NE * 4);
    u16*   aeh     = (u16*)alloc((size_t)NN * 64 * 2);     // aggE split
    u16*   ael     = (u16*)alloc((size_t)NN * 64 * 2);
    u16*   shh_    = (u16*)alloc((size_t)NHH * HD * 2);    // x-split / hh-split
    u16*   shl_    = (u16*)alloc((size_t)NHH * HD * 2);
    u16*   gsh     = (u16*)alloc((size_t)NN * HD * 2);     // aggX / (t+agg) split
    u16*   gsl     = (u16*)alloc((size_t)NN * HD * 2);
    u16*   msh     = (u16*)alloc((size_t)NN * HD * 2);     // m / u split
    u16*   msl     = (u16*)alloc((size_t)NN * HD * 2);
    float* h1      = (float*)alloc((size_t)NN * HD * 4);   // h1 / t1 / t2b fp32
    float* h2      = (float*)alloc((size_t)NN * HD * 4);   // h2 / t2 fp32
    float* gi      = (float*)alloc((size_t)NN * 768 * 4);  // h1-planes early; C768 planes late
    float* gh      = (float*)alloc((size_t)NN * 768 * 4);  // u768 planes mid; k_all/v_all/g1 late
    float* hh      = (float*)alloc((size_t)NHH * HD * 4);
    float* coef    = (float*)alloc((size_t)NN * 4);
    float* wsum    = (float*)alloc(256 * 4);
    float* qrow    = (float*)alloc(256 * 4);
    float* logits  = (float*)alloc((size_t)NHH * 4);
    float* pbuf    = (float*)alloc((size_t)NHH * 4);
    float* scal    = (float*)alloc(256);
    float* ctx     = (float*)alloc(256 * 4);
    float* mvec    = (float*)alloc(256 * 4);
    float* gi3     = (float*)alloc(768 * 4);
    float* gh3     = (float*)alloc(768 * 4);

    // weight split planes
    auto walloc = [&](size_t nel, u16** h, u16** l) {
        *h = (u16*)alloc(nel * 2); *l = (u16*)alloc(nel * 2);
    };
    u16 *wm1h, *wm1l, *wm2h, *wm2l, *wi1h, *wi1l, *wh1h, *wh1l, *wi2h, *wi2l, *wh2h, *wh2l;
    u16 *g1h, *g1l, *g2h, *g2l, *pjh, *pjl, *gwh, *gwl, *kwh, *kwl, *vwh, *vwl;
    walloc(81920, &wm1h, &wm1l);   walloc(81920, &wm2h, &wm2l);
    walloc(196608, &wi1h, &wi1l);  walloc(196608, &wh1h, &wh1l);
    walloc(196608, &wi2h, &wi2l);  walloc(196608, &wh2h, &wh2l);
    walloc(196608, &g1h, &g1l);    walloc(196608, &g2h, &g2l);
    walloc(196608, &pjh, &pjl);    walloc(32768, &gwh, &gwl);
    walloc(65536, &kwh, &kwl);     walloc(65536, &vwh, &vwl);
    u16 *xh = shh_, *xl = shl_;

    // phase aliases (lifetimes disjoint):
    u16*   h1h   = (u16*)gi;                       // h1 planes (DMPNN window)
    u16*   h1l   = h1h + (size_t)NN * HD;
    u16*   c768h = (u16*)gi;                       // GIN output planes (after h1 planes dead)
    u16*   c768l = c768h + (size_t)NN * 768;
    u16*   u768h = (u16*)gh;                       // GIN hop-1 batched output planes
    u16*   u768l = u768h + (size_t)NN * 768;
    float* k_all = gh;                             // attention phase (u768 dead)
    float* v_all = gh + (size_t)NHH * HD;
    float* g1    = gh + (size_t)2 * NHH * HD;

    auto hg = [&](const u16* Ah, const u16* Al, int lda,
                  const u16* Abh, const u16* Abl, int ldab, int Kb,
                  const u16* Wh, const u16* Wl, int ldw, const float* bias,
                  float* C, u16* Chi, u16* Clo, int ldc,
                  int M, int Nc, int K, int flags) {
        int nbx = Nc / 64, nby = (M + 127) / 128;
        hgemm_kernel<<<nbx * nby, 256, 0, stream>>>(Ah, Al, lda, Abh, Abl, ldab, Kb,
                                                    Wh, Wl, ldw, bias, C, Chi, Clo, ldc,
                                                    M, K, flags, nbx);
    };

    // ------------------------------ CSR build ------------------------------
    hipMemsetAsync(cnt, 0, (size_t)NN * 4, stream);
    hist_kernel<<<NE / 256, 256, 0, stream>>>(dst, cnt, NE);
    scan_kernel<<<1, 1024, 0, stream>>>(cnt, row_ptr);
    copy_int_kernel<<<NN / 256, 256, 0, stream>>>(row_ptr, cnt, NN);
    fill_kernel<<<NE / 256, 256, 0, stream>>>(dst, src, cnt, eids, gsrc, NE);
    segsum64_split_kernel<<<NN, 256, 0, stream>>>(row_ptr, eids, eattr, aeh, ael);

    // ------------------------------ one-time splits (single launch) --------
    {
        SplitArgs a;
        const float* srcs[13] = { x, Wmsg1, Wmsg2, wih1, whh1, wih2, whh2,
                                  ginw1, ginw2, projw, gatew1, kw, vw };
        u16* his[13] = { xh, wm1h, wm2h, wi1h, wh1h, wi2h, wh2h, g1h, g2h, pjh, gwh, kwh, vwh };
        u16* los[13] = { xl, wm1l, wm2l, wi1l, wh1l, wi2l, wh2l, g1l, g2l, pjl, gwl, kwl, vwl };
        const int blocks[13] = { 2048, 80, 80, 192, 192, 192, 192, 192, 192, 192, 32, 64, 64 };
        int acc = 0;
        for (int t = 0; t < 13; ++t) { a.src[t] = srcs[t]; a.hi[t] = his[t]; a.lo[t] = los[t]; a.off[t] = acc; acc += blocks[t]; }
        a.off[13] = acc;
        multisplit_kernel<<<acc, 256, 0, stream>>>(a);
    }

    // ------------------------------ DMPNN 1 --------------------------------
    segsum256_split_kernel<<<NN, 256, 0, stream>>>(row_ptr, gsrc, x, gsh, gsl, 0);
    hg(gsh, gsl, HD, aeh, ael, 64, 64, wm1h, wm1l, 320, nullptr,
       nullptr, msh, msl, HD, NN, HD, HD, 0);
    gru_fused_kernel<<<512, 256, 0, stream>>>(msh, msl, xh, xl, x,
                                              wi1h, wi1l, wh1h, wh1l, bih1, bhh1,
                                              h1, h1h, h1l);

    // ------------------------------ DMPNN 2 --------------------------------
    segsum256_split_kernel<<<NN, 256, 0, stream>>>(row_ptr, gsrc, h1, gsh, gsl, 0);
    hg(gsh, gsl, HD, aeh, ael, 64, 64, wm2h, wm2l, 320, nullptr,
       nullptr, msh, msl, HD, NN, HD, HD, 0);
    gru_fused_kernel<<<512, 256, 0, stream>>>(msh, msl, h1h, h1l, h1,
                                              wi2h, wi2l, wh2h, wh2l, bih2, bhh2,
                                              h2, nullptr, nullptr);

    // ------------------------------ GIN towers -----------------------------
    // hop 1 shared input s = h2 + agg(h2); batched over all 3 towers (N=768)
    segsum256_split_kernel<<<NN, 256, 0, stream>>>(row_ptr, gsrc, h2, gsh, gsl, 1);
    hg(gsh, gsl, HD, nullptr, nullptr, 0, 0, g1h, g1l, HD, ginb1,
       nullptr, u768h, u768l, 768, NN, 768, HD, 1);
    // second stage per tower (u768 slices as A)
    hg(u768h, u768l, 768, nullptr, nullptr, 0, 0, g2h, g2l, HD, ginb2,
       nullptr, c768h, c768l, 768, NN, HD, HD, 0);                       // tower0 -> C768[:,0:256)
    hg(u768h + 256, u768l + 256, 768, nullptr, nullptr, 0, 0, g2h + 65536, g2l + 65536, HD, ginb2 + 256,
       h1, nullptr, nullptr, HD, NN, HD, HD, 0);                          // tower1 t1
    hg(u768h + 512, u768l + 512, 768, nullptr, nullptr, 0, 0, g2h + 131072, g2l + 131072, HD, ginb2 + 512,
       h2, nullptr, nullptr, HD, NN, HD, HD, 0);                          // tower2 t2
    // tower 1 hop 2 -> C768 cols [256,512)
    segsum256_split_kernel<<<NN, 256, 0, stream>>>(row_ptr, gsrc, h1, gsh, gsl, 1);
    hg(gsh, gsl, HD, nullptr, nullptr, 0, 0, g1h + 65536, g1l + 65536, HD, ginb1 + 256,
       nullptr, msh, msl, HD, NN, HD, HD, 1);
    hg(msh, msl, HD, nullptr, nullptr, 0, 0, g2h + 65536, g2l + 65536, HD, ginb2 + 256,
       nullptr, c768h + 256, c768l + 256, 768, NN, HD, HD, 0);
    // tower 2 hop 2 -> t2b (h1 slot)
    segsum256_split_kernel<<<NN, 256, 0, stream>>>(row_ptr, gsrc, h2, gsh, gsl, 1);
    hg(gsh, gsl, HD, nullptr, nullptr, 0, 0, g1h + 131072, g1l + 131072, HD, ginb1 + 512,
       nullptr, msh, msl, HD, NN, HD, HD, 1);
    hg(msh, msl, HD, nullptr, nullptr, 0, 0, g2h + 131072, g2l + 131072, HD, ginb2 + 512,
       h1, nullptr, nullptr, HD, NN, HD, HD, 0);
    // tower 2 hop 3 -> C768 cols [512,768)
    segsum256_split_kernel<<<NN, 256, 0, stream>>>(row_ptr, gsrc, h1, gsh, gsl, 1);
    hg(gsh, gsl, HD, nullptr, nullptr, 0, 0, g1h + 131072, g1l + 131072, HD, ginb1 + 512,
       nullptr, msh, msl, HD, NN, HD, HD, 1);
    hg(msh, msl, HD, nullptr, nullptr, 0, 0, g2h + 131072, g2l + 131072, HD, ginb2 + 512,
       nullptr, c768h + 512, c768l + 512, 768, NN, HD, HD, 0);

    // ------------------------------ mix + hh -------------------------------
    hg(c768h, c768l, 768, nullptr, nullptr, 0, 0, pjh, pjl, 768, projb,
       hh, shh_, shl_, HD, NN, HD, 768, 0);
    hhtail_kernel<<<1, 256, 0, stream>>>(rcinit, sinit, hh, shh_, shl_);

    // ------------------------------ gate / skip-sum / sGRU -----------------
    hg(shh_, shl_, HD, nullptr, nullptr, 0, 0, gwh, gwl, HD, gateb1,
       g1, nullptr, nullptr, 128, NN, 128, HD, 1);
    alpha_kernel<<<NN / 4, 256, 0, stream>>>(g1, gatew2, gateb2, rcmask, coef, NN);
    hipMemsetAsync(wsum, 0, 256 * 4, stream);
    colsum_kernel<<<256, 256, 0, stream>>>(hh, coef, wsum, NN, 32);
    gemv256_kernel<<<64, 256, 0, stream>>>(skipW, wsum, rcinit, nullptr, mvec, 256);
    gemv256_kernel<<<192, 256, 0, stream>>>(swih, mvec, nullptr, sbih, gi3, 768);
    gemv256_kernel<<<192, 256, 0, stream>>>(swhh, sinit, nullptr, sbhh, gh3, 768);
    sgru_combine_kernel<<<1, 256, 0, stream>>>(gi3, gh3, sinit, hh, shh_, shl_);

    // ------------------------------ attention row --------------------------
    hg(shh_, shl_, HD, nullptr, nullptr, 0, 0, kwh, kwl, HD, kb,
       k_all, nullptr, nullptr, HD, NHH, HD, HD, 0);
    hg(shh_, shl_, HD, nullptr, nullptr, 0, 0, vwh, vwl, HD, vb,
       v_all, nullptr, nullptr, HD, NHH, HD, HD, 0);
    gemv256_kernel<<<64, 256, 0, stream>>>(qw, hh + (size_t)(NN + 1) * HD, nullptr, qb, qrow, 256);
    logits_kernel<<<(NHH + 3) / 4, 256, 0, stream>>>(k_all, qrow, logits, NHH);
    softmax_prep_kernel<<<1, 1024, 0, stream>>>(logits, pbuf, scal, NHH);
    hipMemsetAsync(ctx, 0, 256 * 4, stream);
    colsum_kernel<<<(NHH + 31) / 32, 256, 0, stream>>>(v_all, pbuf, ctx, NHH, 32);
    final_gemv_kernel<<<64, 256, 0, stream>>>(hh, ow, ob, ctx, scal, (float*)d_out);
}

// Round 6
// 665.904 us; speedup vs baseline: 2.1720x; 1.2188x over previous
//
#include <hip/hip_runtime.h>
#include <hip/hip_bf16.h>

#define NN   8192
#define NE   262144
#define HD   256
#define NHH  8194   // hh rows = N + 2

using f32x4  = __attribute__((ext_vector_type(4))) float;
using bf16x8 = __attribute__((ext_vector_type(8))) short;
typedef unsigned short u16;

__device__ __forceinline__ u16 f2bf(float f) {
    unsigned u = __builtin_bit_cast(unsigned, f);
    u = (u + 0x7FFFu + ((u >> 16) & 1u)) >> 16;
    return (u16)u;
}
__device__ __forceinline__ float bf2f(u16 h) {
    return __builtin_bit_cast(float, (unsigned)h << 16);
}
__device__ __forceinline__ void split1(float a, u16& h, u16& l) {
    h = f2bf(a);
    l = f2bf(a - bf2f(h));   // a - hi is exact in fp32
}
__device__ __forceinline__ void store_split4(u16* hi, u16* lo, size_t off, float4 v) {
    ushort4 h, l;
    split1(v.x, h.x, l.x); split1(v.y, h.y, l.y);
    split1(v.z, h.z, l.z); split1(v.w, h.w, l.w);
    *(ushort4*)(hi + off) = h;
    *(ushort4*)(lo + off) = l;
}

// bijective XCD-aware swizzle (m204)
__device__ __forceinline__ void swz_xy(int nbx, int& bx, int& by) {
    int nwg = gridDim.x;
    int o = blockIdx.x;
    int q = nwg >> 3, r = nwg & 7;
    int xcd = o & 7;
    int base = (xcd < r) ? xcd * (q + 1) : r * (q + 1) + (xcd - r) * q;
    int wg = base + (o >> 3);
    bx = wg % nbx;
    by = wg / nbx;
}

// ---------------------------------------------------------------- CSR build
__global__ void hist_kernel(const int* __restrict__ dst, int* __restrict__ cnt, int E) {
    int e = blockIdx.x * blockDim.x + threadIdx.x;
    if (e < E) atomicAdd(&cnt[dst[e]], 1);
}

__global__ __launch_bounds__(1024) void scan_kernel(const int* __restrict__ cnt, int* __restrict__ row_ptr) {
    __shared__ int sdata[1024];
    int tid = threadIdx.x;
    int v[8], local[8];
    int s = 0;
#pragma unroll
    for (int i = 0; i < 8; i++) v[i] = cnt[tid * 8 + i];
#pragma unroll
    for (int i = 0; i < 8; i++) { local[i] = s; s += v[i]; }
    sdata[tid] = s;
    __syncthreads();
    for (int off = 1; off < 1024; off <<= 1) {
        int t = (tid >= off) ? sdata[tid - off] : 0;
        __syncthreads();
        sdata[tid] += t;
        __syncthreads();
    }
    int base = (tid == 0) ? 0 : sdata[tid - 1];
#pragma unroll
    for (int i = 0; i < 8; i++) row_ptr[tid * 8 + i] = base + local[i];
    if (tid == 1023) row_ptr[8192] = sdata[1023];
}

__global__ void copy_int_kernel(const int* __restrict__ a, int* __restrict__ b, int n) {
    int i = blockIdx.x * blockDim.x + threadIdx.x;
    if (i < n) b[i] = a[i];
}

__global__ void fill_kernel(const int* __restrict__ dst, const int* __restrict__ src,
                            int* __restrict__ cursor, int* __restrict__ eids,
                            int* __restrict__ gsrc, int E) {
    int e = blockIdx.x * blockDim.x + threadIdx.x;
    if (e < E) {
        int pos = atomicAdd(&cursor[dst[e]], 1);
        eids[pos] = e;
        gsrc[pos] = src[e];
    }
}

// ---------------------------------------------- fused fp32 -> bf16x2 splits
struct SplitArgs {
    const float* src[13];
    u16* hi[13];
    u16* lo[13];
    int  off[14];
};
__global__ __launch_bounds__(256) void multisplit_kernel(SplitArgs a) {
    int blk = blockIdx.x;
    int s = 0;
#pragma unroll
    for (int t = 0; t < 13; ++t) if (blk >= a.off[t + 1]) s = t + 1;
    size_t i = ((size_t)(blk - a.off[s]) * 256 + threadIdx.x) * 4;
    float4 v = *(const float4*)(a.src[s] + i);
    store_split4(a.hi[s], a.lo[s], i, v);
}

// --------------------------------------- segment sums -> split bf16 planes
__global__ __launch_bounds__(256) void segsum64_split_kernel(const int* __restrict__ row_ptr,
                                                             const int* __restrict__ idx,
                                                             const float* __restrict__ T,
                                                             u16* __restrict__ outh,
                                                             u16* __restrict__ outl) {
    __shared__ float4 part[15][16];
    const int n    = blockIdx.x;
    const int slot = threadIdx.x >> 4;
    const int fl   = threadIdx.x & 15;
    const int b = row_ptr[n], e = row_ptr[n + 1];
    float4 a0 = make_float4(0.f, 0.f, 0.f, 0.f);
    float4 a1 = make_float4(0.f, 0.f, 0.f, 0.f);
    int i = b + slot;
    for (; i + 16 < e; i += 32) {
        int s0 = idx[i], s1 = idx[i + 16];
        float4 v0 = *(const float4*)(T + (size_t)s0 * 64 + fl * 4);
        float4 v1 = *(const float4*)(T + (size_t)s1 * 64 + fl * 4);
        a0.x += v0.x; a0.y += v0.y; a0.z += v0.z; a0.w += v0.w;
        a1.x += v1.x; a1.y += v1.y; a1.z += v1.z; a1.w += v1.w;
    }
    if (i < e) {
        int s0 = idx[i];
        float4 v0 = *(const float4*)(T + (size_t)s0 * 64 + fl * 4);
        a0.x += v0.x; a0.y += v0.y; a0.z += v0.z; a0.w += v0.w;
    }
    a0.x += a1.x; a0.y += a1.y; a0.z += a1.z; a0.w += a1.w;
    if (slot > 0) part[slot - 1][fl] = a0;
    __syncthreads();
    if (slot == 0) {
#pragma unroll
        for (int t = 0; t < 15; ++t) {
            float4 p = part[t][fl];
            a0.x += p.x; a0.y += p.y; a0.z += p.z; a0.w += p.w;
        }
        store_split4(outh, outl, (size_t)n * 64 + fl * 4, a0);
    }
}

__global__ __launch_bounds__(256) void segsum256_split_kernel(const int* __restrict__ row_ptr,
                                                              const int* __restrict__ idx,
                                                              const float* __restrict__ T,
                                                              u16* __restrict__ outh,
                                                              u16* __restrict__ outl,
                                                              int self) {
    __shared__ float4 partA[7][32];
    __shared__ float4 partB[7][32];
    const int n    = blockIdx.x;
    const int slot = threadIdx.x >> 5;        // 0..7
    const int fl   = threadIdx.x & 31;        // floats [fl*8, fl*8+8)
    const int b = row_ptr[n], e = row_ptr[n + 1];
    float4 aA = make_float4(0.f, 0.f, 0.f, 0.f);
    float4 aB = make_float4(0.f, 0.f, 0.f, 0.f);
    float4 bA = make_float4(0.f, 0.f, 0.f, 0.f);
    float4 bB = make_float4(0.f, 0.f, 0.f, 0.f);
    int i = b + slot;
    for (; i + 8 < e; i += 16) {
        int s0 = idx[i], s1 = idx[i + 8];
        const float* p0 = T + (size_t)s0 * HD + fl * 8;
        const float* p1 = T + (size_t)s1 * HD + fl * 8;
        float4 v0a = *(const float4*)p0;
        float4 v0b = *(const float4*)(p0 + 4);
        float4 v1a = *(const float4*)p1;
        float4 v1b = *(const float4*)(p1 + 4);
        aA.x += v0a.x; aA.y += v0a.y; aA.z += v0a.z; aA.w += v0a.w;
        aB.x += v0b.x; aB.y += v0b.y; aB.z += v0b.z; aB.w += v0b.w;
        bA.x += v1a.x; bA.y += v1a.y; bA.z += v1a.z; bA.w += v1a.w;
        bB.x += v1b.x; bB.y += v1b.y; bB.z += v1b.z; bB.w += v1b.w;
    }
    if (i < e) {
        int s0 = idx[i];
        const float* p0 = T + (size_t)s0 * HD + fl * 8;
        float4 v0a = *(const float4*)p0;
        float4 v0b = *(const float4*)(p0 + 4);
        aA.x += v0a.x; aA.y += v0a.y; aA.z += v0a.z; aA.w += v0a.w;
        aB.x += v0b.x; aB.y += v0b.y; aB.z += v0b.z; aB.w += v0b.w;
    }
    aA.x += bA.x; aA.y += bA.y; aA.z += bA.z; aA.w += bA.w;
    aB.x += bB.x; aB.y += bB.y; aB.z += bB.z; aB.w += bB.w;
    if (slot > 0) { partA[slot - 1][fl] = aA; partB[slot - 1][fl] = aB; }
    __syncthreads();
    if (slot == 0) {
#pragma unroll
        for (int t = 0; t < 7; ++t) {
            float4 pa = partA[t][fl], pb = partB[t][fl];
            aA.x += pa.x; aA.y += pa.y; aA.z += pa.z; aA.w += pa.w;
            aB.x += pb.x; aB.y += pb.y; aB.z += pb.z; aB.w += pb.w;
        }
        if (self) {
            const float* ps = T + (size_t)n * HD + fl * 8;
            float4 sa = *(const float4*)ps;
            float4 sb = *(const float4*)(ps + 4);
            aA.x += sa.x; aA.y += sa.y; aA.z += sa.z; aA.w += sa.w;
            aB.x += sb.x; aB.y += sb.y; aB.z += sb.z; aB.w += sb.w;
        }
        store_split4(outh, outl, (size_t)n * HD + fl * 8, aA);
        store_split4(outh, outl, (size_t)n * HD + fl * 8 + 4, aB);
    }
}

// --------------------------------- LDS-staged split-bf16 3-product MFMA GEMM
// C[M x N] = act( (A ‖ Ab) @ W^T + bias ),  A = Ah + Al (bf16 planes).
// Block: 128 rows x 64 cols, 4 waves of 64x32. BK=64, K = Ka + Kb.
// LDS: A-planes [128][64+8pad], W-planes [64][64+8pad] (pad -> 2-way bank = free).
// Staging: reg-staged, next tile's global loads issued before current MFMAs.
#define LDSA0 0
#define LDSA1 9216
#define LDSW0 18432
#define LDSW1 23040
__global__ __launch_bounds__(256) void hgemm_kernel(
    const u16* __restrict__ Ah, const u16* __restrict__ Al, int lda,
    const u16* __restrict__ Abh, const u16* __restrict__ Abl, int ldab, int Ka, int Kb,
    const u16* __restrict__ Wh, const u16* __restrict__ Wl, int ldw,
    const float* __restrict__ bias,
    float* __restrict__ C, u16* __restrict__ Chi, u16* __restrict__ Clo, int ldc,
    int M, int flags, int nbx) {
    __shared__ __align__(16) u16 lds[27648];
    int bx, by;
    swz_xy(nbx, bx, by);
    const int tid  = threadIdx.x;
    const int wid  = tid >> 6;
    const int lane = tid & 63;
    const int lrow = lane & 15;
    const int ksel = lane >> 4;

    // staging maps: A: 2 threads/row x 4 chunks; W: 4 threads/row x 2 chunks
    const int arow  = tid >> 1, ahalf = tid & 1;
    const int agrow = min(by * 128 + arow, M - 1);
    const int wrow  = tid >> 2, wq = tid & 3;
    const size_t wgoff = (size_t)(bx * 64 + wrow) * ldw + wq * 16;

    const int nt = (Ka + Kb) >> 6;

    bf16x8 ga[4], gb[4], gw[2], gx[2];
    auto loadtile = [&](int t) {
        int kb = t << 6;
        const u16 *ph, *pl; int ld_; int kk;
        if (kb < Ka) { ph = Ah;  pl = Al;  ld_ = lda;  kk = kb; }
        else         { ph = Abh; pl = Abl; ld_ = ldab; kk = kb - Ka; }
        const u16* pa = ph + (size_t)agrow * ld_ + kk + ahalf * 32;
        const u16* pb = pl + (size_t)agrow * ld_ + kk + ahalf * 32;
#pragma unroll
        for (int j = 0; j < 4; ++j) {
            ga[j] = *(const bf16x8*)(pa + j * 8);
            gb[j] = *(const bf16x8*)(pb + j * 8);
        }
        const u16* pw = Wh + wgoff + kb;
        const u16* px = Wl + wgoff + kb;
#pragma unroll
        for (int j = 0; j < 2; ++j) {
            gw[j] = *(const bf16x8*)(pw + j * 8);
            gx[j] = *(const bf16x8*)(px + j * 8);
        }
    };

    f32x4 acc[4][2] = {};
    const int fr0 = (wid >> 1) * 64;   // wave row offset in tile
    const int cr0 = (wid & 1) * 32;    // wave col offset in tile

    loadtile(0);
    for (int t = 0; t < nt; ++t) {
        {   // LDS write of staged tile (auto vmcnt wait on ga..gx)
            u16* da = lds + LDSA0 + arow * 72 + ahalf * 32;
            u16* db = lds + LDSA1 + arow * 72 + ahalf * 32;
#pragma unroll
            for (int j = 0; j < 4; ++j) {
                *(bf16x8*)(da + j * 8) = ga[j];
                *(bf16x8*)(db + j * 8) = gb[j];
            }
            u16* dw = lds + LDSW0 + wrow * 72 + wq * 16;
            u16* dx = lds + LDSW1 + wrow * 72 + wq * 16;
#pragma unroll
            for (int j = 0; j < 2; ++j) {
                *(bf16x8*)(dw + j * 8) = gw[j];
                *(bf16x8*)(dx + j * 8) = gx[j];
            }
        }
        __syncthreads();
        if (t + 1 < nt) loadtile(t + 1);   // prefetch flies under MFMAs
#pragma unroll
        for (int ks = 0; ks < 2; ++ks) {
            bf16x8 fah[4], fal[4], fwh[2], fwl[2];
            const int ko = ks * 32 + ksel * 8;
#pragma unroll
            for (int fi = 0; fi < 4; ++fi) {
                int o = (fr0 + fi * 16 + lrow) * 72 + ko;
                fah[fi] = *(const bf16x8*)(lds + LDSA0 + o);
                fal[fi] = *(const bf16x8*)(lds + LDSA1 + o);
            }
#pragma unroll
            for (int ci = 0; ci < 2; ++ci) {
                int o = (cr0 + ci * 16 + lrow) * 72 + ko;
                fwh[ci] = *(const bf16x8*)(lds + LDSW0 + o);
                fwl[ci] = *(const bf16x8*)(lds + LDSW1 + o);
            }
#pragma unroll
            for (int fi = 0; fi < 4; ++fi)
#pragma unroll
                for (int ci = 0; ci < 2; ++ci) {
                    acc[fi][ci] = __builtin_amdgcn_mfma_f32_16x16x32_bf16(fah[fi], fwh[ci], acc[fi][ci], 0, 0, 0);
                    acc[fi][ci] = __builtin_amdgcn_mfma_f32_16x16x32_bf16(fah[fi], fwl[ci], acc[fi][ci], 0, 0, 0);
                    acc[fi][ci] = __builtin_amdgcn_mfma_f32_16x16x32_bf16(fal[fi], fwh[ci], acc[fi][ci], 0, 0, 0);
                }
        }
        __syncthreads();
    }

#pragma unroll
    for (int fi = 0; fi < 4; ++fi) {
        int rbase = by * 128 + fr0 + fi * 16 + (lane >> 4) * 4;
#pragma unroll
        for (int ci = 0; ci < 2; ++ci) {
            int col = bx * 64 + cr0 + ci * 16 + lrow;
#pragma unroll
            for (int j = 0; j < 4; ++j) {
                int r = rbase + j;
                if (r >= M) continue;
                float v = acc[fi][ci][j];
                if (bias)      v += bias[col];
                if (flags & 1) v = fmaxf(v, 0.f);
                size_t o = (size_t)r * ldc + col;
                if (C) C[o] = v;
                if (Chi) { u16 hb, lb; split1(v, hb, lb); Chi[o] = hb; Clo[o] = lb; }
            }
        }
    }
}

// ----------------------------------------------------------- GRU elementwise
__global__ void gru_combine_kernel(const float* __restrict__ gi, const float* __restrict__ gh,
                                   const float* __restrict__ hprev, float* __restrict__ hout,
                                   u16* __restrict__ hhi, u16* __restrict__ hlo, int total4) {
    int t = blockIdx.x * 256 + threadIdx.x;
    if (t >= total4) return;
    int i4  = t * 4;
    int row = i4 >> 8, f = i4 & 255;
    size_t b = (size_t)row * 768;
    float4 ir = *(const float4*)(gi + b + f);
    float4 iz = *(const float4*)(gi + b + 256 + f);
    float4 in_ = *(const float4*)(gi + b + 512 + f);
    float4 hr = *(const float4*)(gh + b + f);
    float4 hz = *(const float4*)(gh + b + 256 + f);
    float4 hn = *(const float4*)(gh + b + 512 + f);
    float4 hp = *(const float4*)(hprev + (size_t)row * HD + f);
    float4 hv;
#pragma unroll
    for (int j = 0; j < 4; ++j) {
        float irj = ((const float*)&ir)[j], izj = ((const float*)&iz)[j], inj = ((const float*)&in_)[j];
        float hrj = ((const float*)&hr)[j], hzj = ((const float*)&hz)[j], hnj = ((const float*)&hn)[j];
        float r = 1.f / (1.f + expf(-(irj + hrj)));
        float z = 1.f / (1.f + expf(-(izj + hzj)));
        float n = tanhf(inj + r * hnj);
        ((float*)&hv)[j] = (1.f - z) * n + z * ((const float*)&hp)[j];
    }
    size_t o = (size_t)row * HD + f;
    *(float4*)(hout + o) = hv;
    if (hhi) store_split4(hhi, hlo, o, hv);
}

// ------------------------------------------------------------------ epilogue
__global__ void hhtail_kernel(const float* __restrict__ rc, const float* __restrict__ si,
                              float* __restrict__ hh, u16* __restrict__ hhi, u16* __restrict__ hlo) {
    int f = threadIdx.x;
    size_t o1 = (size_t)NN * HD + f, o2 = (size_t)(NN + 1) * HD + f;
    float a = rc[f], b = si[f];
    hh[o1] = a; hh[o2] = b;
    u16 h, l;
    split1(a, h, l); hhi[o1] = h; hlo[o1] = l;
    split1(b, h, l); hhi[o2] = h; hlo[o2] = l;
}

__global__ __launch_bounds__(256) void alpha_kernel(const float* __restrict__ g1, const float* __restrict__ gw2,
                                                    const float* __restrict__ gb2, const int* __restrict__ rcmask,
                                                    float* __restrict__ coef, int N) {
    int node = blockIdx.x * 4 + (threadIdx.x >> 6);
    int lane = threadIdx.x & 63;
    if (node >= N) return;
    float part = g1[(size_t)node * 128 + lane] * gw2[lane]
               + g1[(size_t)node * 128 + 64 + lane] * gw2[64 + lane];
    for (int off = 32; off > 0; off >>= 1) part += __shfl_down(part, off);
    if (lane == 0) {
        float a = 1.f / (1.f + expf(-(part + gb2[0])));
        coef[node] = rcmask[node] ? 0.f : a;
    }
}

__global__ __launch_bounds__(256) void colsum_kernel(const float* __restrict__ X, const float* __restrict__ coef,
                                                     float* __restrict__ out, int rows_total, int rows_per_blk) {
    int f  = threadIdx.x;
    int r0 = blockIdx.x * rows_per_blk;
    int r1 = r0 + rows_per_blk; if (r1 > rows_total) r1 = rows_total;
    float a0 = 0.f, a1 = 0.f;
    int r = r0;
    for (; r + 1 < r1; r += 2) {
        a0 += coef[r]     * X[(size_t)r * HD + f];
        a1 += coef[r + 1] * X[(size_t)(r + 1) * HD + f];
    }
    if (r < r1) a0 += coef[r] * X[(size_t)r * HD + f];
    atomicAdd(&out[f], a0 + a1);
}

__global__ __launch_bounds__(256) void gemv256_kernel(const float* __restrict__ M,
                                                      const float* __restrict__ vA,
                                                      const float* __restrict__ vB,
                                                      const float* __restrict__ bias,
                                                      float* __restrict__ out, int R) {
    int row  = blockIdx.x * 4 + (threadIdx.x >> 6);
    int lane = threadIdx.x & 63;
    if (row >= R) return;
    float4 v = *(const float4*)(vA + lane * 4);
    if (vB) {
        float4 b = *(const float4*)(vB + lane * 4);
        v.x += b.x; v.y += b.y; v.z += b.z; v.w += b.w;
    }
    float4 m = *(const float4*)(M + (size_t)row * 256 + lane * 4);
    float p = m.x * v.x + m.y * v.y + m.z * v.z + m.w * v.w;
    for (int off = 32; off > 0; off >>= 1) p += __shfl_down(p, off);
    if (lane == 0) out[row] = p + (bias ? bias[row] : 0.f);
}

__global__ void sgru_combine_kernel(const float* __restrict__ gi3, const float* __restrict__ gh3,
                                    const float* __restrict__ sinit,
                                    float* __restrict__ hh, u16* __restrict__ hhi, u16* __restrict__ hlo) {
    int f = threadIdx.x;
    float gir = gi3[f], giz = gi3[256 + f], gin_ = gi3[512 + f];
    float ghr = gh3[f], ghz = gh3[256 + f], ghn  = gh3[512 + f];
    float r = 1.f / (1.f + expf(-(gir + ghr)));
    float z = 1.f / (1.f + expf(-(giz + ghz)));
    float n = tanhf(gin_ + r * ghn);
    float hv = (1.f - z) * n + z * sinit[f];
    size_t o = (size_t)(NN + 1) * HD + f;
    hh[o] = hv;
    u16 h, l; split1(hv, h, l); hhi[o] = h; hlo[o] = l;
}

__global__ __launch_bounds__(256) void logits_kernel(const float* __restrict__ kall, const float* __restrict__ qrow,
                                                     float* __restrict__ logits, int n) {
    int j    = blockIdx.x * 4 + (threadIdx.x >> 6);
    int lane = threadIdx.x & 63;
    if (j >= n) return;
    float4 q = *(const float4*)(qrow + lane * 4);
    float4 k = *(const float4*)(kall + (size_t)j * HD + lane * 4);
    float part = q.x * k.x + q.y * k.y + q.z * k.z + q.w * k.w;
    for (int off = 32; off > 0; off >>= 1) part += __shfl_down(part, off);
    if (lane == 0) logits[j] = part * 0.0625f;   // / sqrt(256)
}

__global__ __launch_bounds__(1024) void softmax_prep_kernel(const float* __restrict__ logits, float* __restrict__ p,
                                                            float* __restrict__ scal, int n) {
    __shared__ float sd[1024];
    int tid = threadIdx.x;
    float mx = -1e30f;
    for (int j = tid; j < n; j += 1024) mx = fmaxf(mx, logits[j]);
    sd[tid] = mx;
    __syncthreads();
    for (int off = 512; off > 0; off >>= 1) { if (tid < off) sd[tid] = fmaxf(sd[tid], sd[tid + off]); __syncthreads(); }
    float m = sd[0];
    __syncthreads();
    float s = 0.f;
    for (int j = tid; j < n; j += 1024) { float e = expf(logits[j] - m); p[j] = e; s += e; }
    sd[tid] = s;
    __syncthreads();
    for (int off = 512; off > 0; off >>= 1) { if (tid < off) sd[tid] += sd[tid + off]; __syncthreads(); }
    if (tid == 0) scal[0] = sd[0];
}

__global__ __launch_bounds__(256) void final_gemv_kernel(const float* __restrict__ hh,
                                                         const float* __restrict__ ow,
                                                         const float* __restrict__ ob,
                                                         const float* __restrict__ ctx,
                                                         const float* __restrict__ scal,
                                                         float* __restrict__ out) {
    int row  = blockIdx.x * 4 + (threadIdx.x >> 6);
    int lane = threadIdx.x & 63;
    float4 c = *(const float4*)(ctx + lane * 4);
    float4 m = *(const float4*)(ow + (size_t)row * 256 + lane * 4);
    float p = m.x * c.x + m.y * c.y + m.z * c.z + m.w * c.w;
    for (int off = 32; off > 0; off >>= 1) p += __shfl_down(p, off);
    if (lane == 0) {
        float val = hh[(size_t)(NN + 1) * HD + row] + p / scal[0] + ob[row];
        out[row] = fmaxf(val, 0.f);
    }
}

// ---------------------------------------------------------------------------
extern "C" void kernel_launch(void* const* d_in, const int* in_sizes, int n_in,
                              void* d_out, int out_size, void* d_ws, size_t ws_size,
                              hipStream_t stream) {
    const float* x      = (const float*)d_in[0];
    const int*   ei     = (const int*)  d_in[1];
    const float* eattr  = (const float*)d_in[2];
    const int*   rcmask = (const int*)  d_in[3];
    const float* Wmsg1  = (const float*)d_in[4];
    const float* wih1   = (const float*)d_in[5];
    const float* whh1   = (const float*)d_in[6];
    const float* bih1   = (const float*)d_in[7];
    const float* bhh1   = (const float*)d_in[8];
    const float* Wmsg2  = (const float*)d_in[9];
    const float* wih2   = (const float*)d_in[10];
    const float* whh2   = (const float*)d_in[11];
    const float* bih2   = (const float*)d_in[12];
    const float* bhh2   = (const float*)d_in[13];
    const float* ginw1  = (const float*)d_in[14];
    const float* ginb1  = (const float*)d_in[15];
    const float* ginw2  = (const float*)d_in[16];
    const float* ginb2  = (const float*)d_in[17];
    const float* projw  = (const float*)d_in[18];
    const float* projb  = (const float*)d_in[19];
    const float* qw     = (const float*)d_in[20];
    const float* qb     = (const float*)d_in[21];
    const float* kw     = (const float*)d_in[22];
    const float* kb     = (const float*)d_in[23];
    const float* vw     = (const float*)d_in[24];
    const float* vb     = (const float*)d_in[25];
    const float* ow     = (const float*)d_in[26];
    const float* ob     = (const float*)d_in[27];
    const float* gatew1 = (const float*)d_in[28];
    const float* gateb1 = (const float*)d_in[29];
    const float* gatew2 = (const float*)d_in[30];
    const float* gateb2 = (const float*)d_in[31];
    const float* skipW  = (const float*)d_in[32];
    const float* swih   = (const float*)d_in[33];
    const float* swhh   = (const float*)d_in[34];
    const float* sbih   = (const float*)d_in[35];
    const float* sbhh   = (const float*)d_in[36];
    const float* rcinit = (const float*)d_in[37];
    const float* sinit  = (const float*)d_in[38];

    const int* src = ei;
    const int* dst = ei + NE;

    // ---------------- workspace layout -------------------------------------
    char*  w   = (char*)d_ws;
    size_t off = 0;
    auto alloc = [&](size_t bytes) -> void* {
        void* p = w + off;
        off = (off + bytes + 255) & ~(size_t)255;
        return p;
    };
    int*   cnt     = (int*)alloc((size_t)NN * 4);
    int*   row_ptr = (int*)alloc((size_t)(NN + 1) * 4);
    int*   eids    = (int*)alloc((size_t)NE * 4);
    int*   gsrc    = (int*)alloc((size_t)NE * 4);
    u16*   aeh     = (u16*)alloc((size_t)NN * 64 * 2);     // aggE split
    u16*   ael     = (u16*)alloc((size_t)NN * 64 * 2);
    u16*   shh_    = (u16*)alloc((size_t)NHH * HD * 2);    // x / h1 / hh planes
    u16*   shl_    = (u16*)alloc((size_t)NHH * HD * 2);
    u16*   gsh     = (u16*)alloc((size_t)NN * HD * 2);     // agg split
    u16*   gsl     = (u16*)alloc((size_t)NN * HD * 2);
    u16*   msh     = (u16*)alloc((size_t)NN * HD * 2);     // m / u split
    u16*   msl     = (u16*)alloc((size_t)NN * HD * 2);
    float* h1      = (float*)alloc((size_t)NN * HD * 4);   // h1 / t1 / t2b fp32
    float* h2      = (float*)alloc((size_t)NN * HD * 4);   // h2 / t2 fp32
    float* gi      = (float*)alloc((size_t)NN * 768 * 4);  // gi fp32; C768 planes late
    float* gh      = (float*)alloc((size_t)NN * 768 * 4);  // gh fp32; u768 planes / k,v late
    float* hh      = (float*)alloc((size_t)NHH * HD * 4);
    float* coef    = (float*)alloc((size_t)NN * 4);
    float* wsum    = (float*)alloc(256 * 4);
    float* qrow    = (float*)alloc(256 * 4);
    float* logits  = (float*)alloc((size_t)NHH * 4);
    float* pbuf    = (float*)alloc((size_t)NHH * 4);
    float* scal    = (float*)alloc(256);
    float* ctx     = (float*)alloc(256 * 4);
    float* mvec    = (float*)alloc(256 * 4);
    float* gi3     = (float*)alloc(768 * 4);
    float* gh3     = (float*)alloc(768 * 4);

    auto walloc = [&](size_t nel, u16** h, u16** l) {
        *h = (u16*)alloc(nel * 2); *l = (u16*)alloc(nel * 2);
    };
    u16 *wm1h, *wm1l, *wm2h, *wm2l, *wi1h, *wi1l, *wh1h, *wh1l, *wi2h, *wi2l, *wh2h, *wh2l;
    u16 *g1h, *g1l, *g2h, *g2l, *pjh, *pjl, *gwh, *gwl, *kwh, *kwl, *vwh, *vwl;
    walloc(81920, &wm1h, &wm1l);   walloc(81920, &wm2h, &wm2l);
    walloc(196608, &wi1h, &wi1l);  walloc(196608, &wh1h, &wh1l);
    walloc(196608, &wi2h, &wi2l);  walloc(196608, &wh2h, &wh2l);
    walloc(196608, &g1h, &g1l);    walloc(196608, &g2h, &g2l);
    walloc(196608, &pjh, &pjl);    walloc(32768, &gwh, &gwl);
    walloc(65536, &kwh, &kwl);     walloc(65536, &vwh, &vwl);
    u16 *xh = shh_, *xl = shl_;

    // phase aliases (lifetimes disjoint)
    u16*   c768h = (u16*)gi;                       // GIN output planes (gi fp32 dead)
    u16*   c768l = c768h + (size_t)NN * 768;
    u16*   u768h = (u16*)gh;                       // GIN hop-1 batched planes (gh fp32 dead)
    u16*   u768l = u768h + (size_t)NN * 768;
    float* k_all = gh;                             // attention phase (u768 dead)
    float* v_all = gh + (size_t)NHH * HD;
    float* g1    = gh + (size_t)2 * NHH * HD;

    auto hg = [&](const u16* Ah, const u16* Al, int lda,
                  const u16* Abh, const u16* Abl, int ldab, int Ka, int Kb,
                  const u16* Wh, const u16* Wl, int ldw, const float* bias,
                  float* C, u16* Chi, u16* Clo, int ldc,
                  int M, int Nc, int flags) {
        int nbx = Nc / 64, nby = (M + 127) / 128;
        hgemm_kernel<<<nbx * nby, 256, 0, stream>>>(Ah, Al, lda, Abh, Abl, ldab, Ka, Kb,
                                                    Wh, Wl, ldw, bias, C, Chi, Clo, ldc,
                                                    M, flags, nbx);
    };

    // ------------------------------ CSR build ------------------------------
    hipMemsetAsync(cnt, 0, (size_t)NN * 4, stream);
    hist_kernel<<<NE / 256, 256, 0, stream>>>(dst, cnt, NE);
    scan_kernel<<<1, 1024, 0, stream>>>(cnt, row_ptr);
    copy_int_kernel<<<NN / 256, 256, 0, stream>>>(row_ptr, cnt, NN);
    fill_kernel<<<NE / 256, 256, 0, stream>>>(dst, src, cnt, eids, gsrc, NE);
    segsum64_split_kernel<<<NN, 256, 0, stream>>>(row_ptr, eids, eattr, aeh, ael);

    // ------------------------------ one-time splits ------------------------
    {
        SplitArgs a;
        const float* srcs[13] = { x, Wmsg1, Wmsg2, wih1, whh1, wih2, whh2,
                                  ginw1, ginw2, projw, gatew1, kw, vw };
        u16* his[13] = { xh, wm1h, wm2h, wi1h, wh1h, wi2h, wh2h, g1h, g2h, pjh, gwh, kwh, vwh };
        u16* los[13] = { xl, wm1l, wm2l, wi1l, wh1l, wi2l, wh2l, g1l, g2l, pjl, gwl, kwl, vwl };
        const int blocks[13] = { 2048, 80, 80, 192, 192, 192, 192, 192, 192, 192, 32, 64, 64 };
        int acc = 0;
        for (int t = 0; t < 13; ++t) { a.src[t] = srcs[t]; a.hi[t] = his[t]; a.lo[t] = los[t]; a.off[t] = acc; acc += blocks[t]; }
        a.off[13] = acc;
        multisplit_kernel<<<acc, 256, 0, stream>>>(a);
    }

    // ------------------------------ DMPNN 1 --------------------------------
    segsum256_split_kernel<<<NN, 256, 0, stream>>>(row_ptr, gsrc, x, gsh, gsl, 0);
    hg(gsh, gsl, HD, aeh, ael, 64, HD, 64, wm1h, wm1l, 320, nullptr,
       nullptr, msh, msl, HD, NN, HD, 0);
    hg(msh, msl, HD, nullptr, nullptr, 0, HD, 0, wi1h, wi1l, HD, bih1,
       gi, nullptr, nullptr, 768, NN, 768, 0);
    hg(shh_, shl_, HD, nullptr, nullptr, 0, HD, 0, wh1h, wh1l, HD, bhh1,
       gh, nullptr, nullptr, 768, NN, 768, 0);
    gru_combine_kernel<<<NN * HD / 1024, 256, 0, stream>>>(gi, gh, x, h1, shh_, shl_, NN * HD / 4);

    // ------------------------------ DMPNN 2 --------------------------------
    segsum256_split_kernel<<<NN, 256, 0, stream>>>(row_ptr, gsrc, h1, gsh, gsl, 0);
    hg(gsh, gsl, HD, aeh, ael, 64, HD, 64, wm2h, wm2l, 320, nullptr,
       nullptr, msh, msl, HD, NN, HD, 0);
    hg(msh, msl, HD, nullptr, nullptr, 0, HD, 0, wi2h, wi2l, HD, bih2,
       gi, nullptr, nullptr, 768, NN, 768, 0);
    hg(shh_, shl_, HD, nullptr, nullptr, 0, HD, 0, wh2h, wh2l, HD, bhh2,
       gh, nullptr, nullptr, 768, NN, 768, 0);
    gru_combine_kernel<<<NN * HD / 1024, 256, 0, stream>>>(gi, gh, h1, h2, nullptr, nullptr, NN * HD / 4);

    // ------------------------------ GIN towers -----------------------------
    segsum256_split_kernel<<<NN, 256, 0, stream>>>(row_ptr, gsrc, h2, gsh, gsl, 1);
    hg(gsh, gsl, HD, nullptr, nullptr, 0, HD, 0, g1h, g1l, HD, ginb1,
       nullptr, u768h, u768l, 768, NN, 768, 1);
    hg(u768h, u768l, 768, nullptr, nullptr, 0, HD, 0, g2h, g2l, HD, ginb2,
       nullptr, c768h, c768l, 768, NN, HD, 0);
    hg(u768h + 256, u768l + 256, 768, nullptr, nullptr, 0, HD, 0, g2h + 65536, g2l + 65536, HD, ginb2 + 256,
       h1, nullptr, nullptr, HD, NN, HD, 0);
    hg(u768h + 512, u768l + 512, 768, nullptr, nullptr, 0, HD, 0, g2h + 131072, g2l + 131072, HD, ginb2 + 512,
       h2, nullptr, nullptr, HD, NN, HD, 0);
    // tower 1 hop 2 -> C768 cols [256,512)
    segsum256_split_kernel<<<NN, 256, 0, stream>>>(row_ptr, gsrc, h1, gsh, gsl, 1);
    hg(gsh, gsl, HD, nullptr, nullptr, 0, HD, 0, g1h + 65536, g1l + 65536, HD, ginb1 + 256,
       nullptr, msh, msl, HD, NN, HD, 1);
    hg(msh, msl, HD, nullptr, nullptr, 0, HD, 0, g2h + 65536, g2l + 65536, HD, ginb2 + 256,
       nullptr, c768h + 256, c768l + 256, 768, NN, HD, 0);
    // tower 2 hop 2 -> t2b (h1 slot)
    segsum256_split_kernel<<<NN, 256, 0, stream>>>(row_ptr, gsrc, h2, gsh, gsl, 1);
    hg(gsh, gsl, HD, nullptr, nullptr, 0, HD, 0, g1h + 131072, g1l + 131072, HD, ginb1 + 512,
       nullptr, msh, msl, HD, NN, HD, 1);
    hg(msh, msl, HD, nullptr, nullptr, 0, HD, 0, g2h + 131072, g2l + 131072, HD, ginb2 + 512,
       h1, nullptr, nullptr, HD, NN, HD, 0);
    // tower 2 hop 3 -> C768 cols [512,768)
    segsum256_split_kernel<<<NN, 256, 0, stream>>>(row_ptr, gsrc, h1, gsh, gsl, 1);
    hg(gsh, gsl, HD, nullptr, nullptr, 0, HD, 0, g1h + 131072, g1l + 131072, HD, ginb1 + 512,
       nullptr, msh, msl, HD, NN, HD, 1);
    hg(msh, msl, HD, nullptr, nullptr, 0, HD, 0, g2h + 131072, g2l + 131072, HD, ginb2 + 512,
       nullptr, c768h + 512, c768l + 512, 768, NN, HD, 0);

    // ------------------------------ mix + hh -------------------------------
    hg(c768h, c768l, 768, nullptr, nullptr, 0, 768, 0, pjh, pjl, 768, projb,
       hh, shh_, shl_, HD, NN, HD, 0);
    hhtail_kernel<<<1, 256, 0, stream>>>(rcinit, sinit, hh, shh_, shl_);

    // ------------------------------ gate / skip-sum / sGRU -----------------
    hg(shh_, shl_, HD, nullptr, nullptr, 0, HD, 0, gwh, gwl, HD, gateb1,
       g1, nullptr, nullptr, 128, NN, 128, 1);
    alpha_kernel<<<NN / 4, 256, 0, stream>>>(g1, gatew2, gateb2, rcmask, coef, NN);
    hipMemsetAsync(wsum, 0, 256 * 4, stream);
    colsum_kernel<<<256, 256, 0, stream>>>(hh, coef, wsum, NN, 32);
    gemv256_kernel<<<64, 256, 0, stream>>>(skipW, wsum, rcinit, nullptr, mvec, 256);
    gemv256_kernel<<<192, 256, 0, stream>>>(swih, mvec, nullptr, sbih, gi3, 768);
    gemv256_kernel<<<192, 256, 0, stream>>>(swhh, sinit, nullptr, sbhh, gh3, 768);
    sgru_combine_kernel<<<1, 256, 0, stream>>>(gi3, gh3, sinit, hh, shh_, shl_);

    // ------------------------------ attention row --------------------------
    hg(shh_, shl_, HD, nullptr, nullptr, 0, HD, 0, kwh, kwl, HD, kb,
       k_all, nullptr, nullptr, HD, NHH, HD, 0);
    hg(shh_, shl_, HD, nullptr, nullptr, 0, HD, 0, vwh, vwl, HD, vb,
       v_all, nullptr, nullptr, HD, NHH, HD, 0);
    gemv256_kernel<<<64, 256, 0, stream>>>(qw, hh + (size_t)(NN + 1) * HD, nullptr, qb, qrow, 256);
    logits_kernel<<<(NHH + 3) / 4, 256, 0, stream>>>(k_all, qrow, logits, NHH);
    softmax_prep_kernel<<<1, 1024, 0, stream>>>(logits, pbuf, scal, NHH);
    hipMemsetAsync(ctx, 0, 256 * 4, stream);
    colsum_kernel<<<(NHH + 31) / 32, 256, 0, stream>>>(v_all, pbuf, ctx, NHH, 32);
    final_gemv_kernel<<<64, 256, 0, stream>>>(hh, ow, ob, ctx, scal, (float*)d_out);
}